// Round 2
// baseline (787.532 us; speedup 1.0000x reference)
//
#include <hip/hip_runtime.h>
#include <math.h>
#include <float.h>

// Problem constants (B=32, C=32, H=W=32, V=4096)
#define BS    32
#define CH    32
#define HH    32
#define VV    4096
#define FELEMS (BS*CH*HH*HH)   // 1048576
#define NROWS_TOTAL 43680      // sum over scales of B*pn*pn

typedef unsigned short ushort_t;
typedef unsigned long long u64_t;
typedef _Float16 half_t;
typedef __attribute__((ext_vector_type(8))) _Float16 half8;
typedef __attribute__((ext_vector_type(4))) float floatx4;

// 2-way fp16 split: x ~= h + l, residual <= 2^-22 |x|
__device__ inline void split2(float x, half_t* h, half_t* l) {
    half_t hh = (half_t)x;
    float r = x - (float)hh;
    *h = hh;
    *l = (half_t)r;
}

// fp32 -> sortable-descending key32 (bigger score => smaller key)
__device__ inline unsigned score_key32(float s) {
    unsigned u = __builtin_bit_cast(unsigned, s);
    unsigned m = (u & 0x80000000u) ? ~u : (u | 0x80000000u);  // monotone asc
    return ~m;                                                 // desc
}

// ---------------------------------------------------------------------------
// prep (grid 1024x256): emb fp16-split + nesqh, zero f_hat output,
// init pk keys to +inf, AND pool si=0 (pn=1: block = (b,c) pair, mean over
// 1024 px -> zhi/zlo) with per-block sumsq partials (deterministic, no
// atomics, no zero-init) for the loss.
__global__ __launch_bounds__(256) void prep_kernel(const float* __restrict__ f,
                                                   const float* __restrict__ emb,
                                                   half_t* __restrict__ ehi,
                                                   half_t* __restrict__ elo,
                                                   float* __restrict__ nesqh,
                                                   float* __restrict__ laccp,
                                                   half_t* __restrict__ zhi,
                                                   half_t* __restrict__ zlo,
                                                   u64_t* __restrict__ pk,
                                                   float* __restrict__ dout) {
    int gid = blockIdx.x * 256 + threadIdx.x;      // 262144 threads
    float4 z4 = {0.f, 0.f, 0.f, 0.f};
    *(float4*)(dout + (size_t)gid * 4) = z4;
    if (gid < NROWS_TOTAL) pk[gid] = ~0ull;        // +inf keys
    if (gid < VV) {
        int v = gid;
        const float* ep = emb + (size_t)v * CH;
        float s = 0.f;
        half_t h[CH], l[CH];
#pragma unroll
        for (int i = 0; i < CH; i++) {
            float e = ep[i];
            s = fmaf(e, e, s);
            split2(e, &h[i], &l[i]);
        }
        nesqh[v] = -0.5f * s;
#pragma unroll
        for (int q = 0; q < 4; q++) {
            half8 H, L;
#pragma unroll
            for (int k = 0; k < 8; k++) {
                H[k] = h[q * 8 + k];
                L[k] = l[q * 8 + k];
            }
            *(half8*)(ehi + (size_t)v * CH + q * 8) = H;
            *(half8*)(elo + (size_t)v * CH + q * 8) = L;
        }
    }

    // pool si=0: pair = blockIdx.x = b*32 + c; base = f + pair*1024
    const int pair = blockIdx.x;
    const float* base = f + (size_t)pair * 1024;
    float s = 0.f, s2 = 0.f;
    for (int p = threadIdx.x; p < 1024; p += 256) {
        float v = base[p];
        s += v;
        s2 = fmaf(v, v, s2);
    }
    __shared__ float sh[256], sh2[256];
    sh[threadIdx.x] = s;
    sh2[threadIdx.x] = s2;
    __syncthreads();
    for (int o = 128; o > 0; o >>= 1) {
        if (threadIdx.x < o) {
            sh[threadIdx.x]  += sh[threadIdx.x + o];
            sh2[threadIdx.x] += sh2[threadIdx.x + o];
        }
        __syncthreads();
    }
    if (threadIdx.x == 0) {
        split2(sh[0] * (1.0f / 1024.0f), &zhi[pair], &zlo[pair]);
        laccp[pair] = sh2[0];      // deterministic partial, summed in finalize
    }
}

// ---------------------------------------------------------------------------
// 3-MFMA fp16 score chain for one 16-row group vs one 16-code tile
// score = z.e - 0.5|e|^2 = ah.bh + ah.bl + al.bh  (al.bl <= 2^-22 dropped)
__device__ inline floatx4 score_chain(half8 ah, half8 al,
                                      half8 bh, half8 bl, floatx4 ehv) {
    floatx4 acc;
    acc = __builtin_amdgcn_mfma_f32_16x16x32_f16(ah, bh, ehv, 0, 0, 0);
    acc = __builtin_amdgcn_mfma_f32_16x16x32_f16(ah, bl, acc, 0, 0, 0);
    acc = __builtin_amdgcn_mfma_f32_16x16x32_f16(al, bh, acc, 0, 0, 0);
    return acc;
}

__device__ inline void sel4(const floatx4& acc, int v, float* best, int* bidx) {
#pragma unroll
    for (int r = 0; r < 4; r++) {
        // strict >: lane-local scan is increasing v -> keeps lowest v on tie
        if (acc[r] > best[r]) { best[r] = acc[r]; bidx[r] = v; }
    }
}

// argmin core (1-deep prefetch — the proven fastest of four structural
// variants: 2-deep pipe, VS ladders, pooled-stage all regressed or tied).
// Wave wv scans TPW v-tiles from t0+wv*TPW over RT 16-row tiles.
// Deferred-select interleave (RT>=2). Winner per row merged cross-block via
// packed-key atomicMin (max score, lowest idx on tie == jnp.argmin).
template <int RT, int TPW>
__device__ inline void argmin_body(const half8* a1, const half8* a2,
                                   const half_t* __restrict__ ehi,
                                   const half_t* __restrict__ elo,
                                   const float* __restrict__ nesqh,
                                   u64_t* __restrict__ pk, int row0, int t0) {
    const int tid  = threadIdx.x;
    const int wv   = tid >> 6;
    const int lane = tid & 63;
    const int col  = lane & 15;
    const int quad = lane >> 4;

    float best[RT][4];
    int   bidx[RT][4];
#pragma unroll
    for (int rt = 0; rt < RT; rt++)
#pragma unroll
        for (int r = 0; r < 4; r++) { best[rt][r] = -FLT_MAX; bidx[rt][r] = 0; }

    int t = t0 + wv * TPW;
    const int tend = t + TPW;

    // prefetch tile t
    size_t eoff = ((size_t)((t << 4) + col) << 5) + (quad << 3);
    half8 nb1 = *(const half8*)(ehi + eoff);
    half8 nb2 = *(const half8*)(elo + eoff);
    float neh = nesqh[(t << 4) + col];

    floatx4 acc[RT];
    int vprev = 0;
    if (RT > 1) acc[RT - 1] = floatx4{-FLT_MAX, -FLT_MAX, -FLT_MAX, -FLT_MAX};

    for (; t < tend; t++) {
        const half8 b1 = nb1, b2 = nb2;
        const floatx4 ehv = {neh, neh, neh, neh};
        const int vcur = (t << 4) + col;
        // prefetch t+1 (clamped) before consuming current
        const int tn = (t + 1 < tend) ? (t + 1) : t;
        const size_t eoff2 = ((size_t)((tn << 4) + col) << 5) + (quad << 3);
        nb1 = *(const half8*)(ehi + eoff2);
        nb2 = *(const half8*)(elo + eoff2);
        neh = nesqh[(tn << 4) + col];

        if (RT == 1) {
            acc[0] = score_chain(a1[0], a2[0], b1, b2, ehv);
            sel4(acc[0], vcur, best[0], bidx[0]);
        } else {
            acc[0] = score_chain(a1[0], a2[0], b1, b2, ehv);
            sel4(acc[RT - 1], vprev, best[RT - 1], bidx[RT - 1]);  // deferred
#pragma unroll
            for (int rt = 1; rt < RT; rt++) {
                acc[rt] = score_chain(a1[rt], a2[rt], b1, b2, ehv);
                sel4(acc[rt - 1], vcur, best[rt - 1], bidx[rt - 1]);
            }
            vprev = vcur;
        }
    }
    if (RT > 1) sel4(acc[RT - 1], vprev, best[RT - 1], bidx[RT - 1]);

    // reduce across the 16 cols (v within tile) of each quad group
#pragma unroll
    for (int m = 1; m < 16; m <<= 1) {
#pragma unroll
        for (int rt = 0; rt < RT; rt++)
#pragma unroll
            for (int r = 0; r < 4; r++) {
                float s2 = __shfl_xor(best[rt][r], m, 64);
                int   v2 = __shfl_xor(bidx[rt][r], m, 64);
                if (s2 > best[rt][r] ||
                    (s2 == best[rt][r] && v2 < bidx[rt][r])) {
                    best[rt][r] = s2; bidx[rt][r] = v2;
                }
            }
    }

    __shared__ float sbs[4 * RT * 16];
    __shared__ int   sbi[4 * RT * 16];
    if (col == 0) {
#pragma unroll
        for (int rt = 0; rt < RT; rt++)
#pragma unroll
            for (int r = 0; r < 4; r++) {
                int row = rt * 16 + (quad << 2) + r;
                sbs[wv * RT * 16 + row] = best[rt][r];
                sbi[wv * RT * 16 + row] = bidx[rt][r];
            }
    }
    __syncthreads();
    if (tid < RT * 16) {
        float s = sbs[tid];
        int   v = sbi[tid];
        for (int w = 1; w < 4; w++) {
            float s2 = sbs[w * RT * 16 + tid];
            int   v2 = sbi[w * RT * 16 + tid];
            if (s2 > s || (s2 == s && v2 < v)) { s = s2; v = v2; }
        }
        u64_t key = ((u64_t)score_key32(s) << 32) | (unsigned)v;
        atomicMin(pk + row0 + tid, key);
    }
}

// generic stage: z-splits from memory (si=0 only now). grid = (nRowBlocks, VS)
template <int RT, int VS>
__global__ __launch_bounds__(256) void argmin_stage(const half_t* __restrict__ zhi,
                                                    const half_t* __restrict__ zlo,
                                                    const half_t* __restrict__ ehi,
                                                    const half_t* __restrict__ elo,
                                                    const float* __restrict__ nesqh,
                                                    u64_t* __restrict__ pk) {
    const int lane = threadIdx.x & 63;
    const int col  = lane & 15;
    const int quad = lane >> 4;
    const int row0 = blockIdx.x * (16 * RT);

    half8 a1[RT], a2[RT];
#pragma unroll
    for (int rt = 0; rt < RT; rt++) {
        size_t off = ((size_t)(row0 + rt * 16 + col) << 5) + (quad << 3);
        a1[rt] = *(const half8*)(zhi + off);
        a2[rt] = *(const half8*)(zlo + off);
    }
    argmin_body<RT, 64 / VS>(a1, a2, ehi, elo, nesqh, pk,
                             row0, (int)blockIdx.y * (256 / VS));
}

// zp stage (si=1..4): pooled z comes as NSLOT fp32 partial sums written by the
// previous conv's epilogue. Sum partials in fixed slot order, scale by the
// exact power-of-two 1/ps'^2, split2 in-register. Row-coalesced loads
// (wave reads 16 contiguous 128B rows).
template <int RT, int VS, int NSLOT, int PN>
__global__ __launch_bounds__(256) void argmin_zp(const float* __restrict__ zp,
                                                 const half_t* __restrict__ ehi,
                                                 const half_t* __restrict__ elo,
                                                 const float* __restrict__ nesqh,
                                                 u64_t* __restrict__ pk) {
    const int lane = threadIdx.x & 63;
    const int col  = lane & 15;
    const int quad = lane >> 4;
    const int row0 = blockIdx.x * (16 * RT);
    constexpr int ZSTR = BS * PN * PN * CH;
    constexpr int PSP  = 32 / PN;
    const float scale = 1.0f / (float)(PSP * PSP);

    half8 a1[RT], a2[RT];
#pragma unroll
    for (int rt = 0; rt < RT; rt++) {
        const float* p = zp + (size_t)(row0 + rt * 16 + col) * CH + (quad << 3);
        float4 v0 = *(const float4*)p;
        float4 v1 = *(const float4*)(p + 4);
#pragma unroll
        for (int sl = 1; sl < NSLOT; sl++) {
            float4 u0 = *(const float4*)(p + (size_t)sl * ZSTR);
            float4 u1 = *(const float4*)(p + (size_t)sl * ZSTR + 4);
            v0.x += u0.x; v0.y += u0.y; v0.z += u0.z; v0.w += u0.w;
            v1.x += u1.x; v1.y += u1.y; v1.z += u1.z; v1.w += u1.w;
        }
        float s[8] = {v0.x, v0.y, v0.z, v0.w, v1.x, v1.y, v1.z, v1.w};
#pragma unroll
        for (int k = 0; k < 8; k++) {
            half_t h, l;
            split2(s[k] * scale, &h, &l);
            a1[rt][k] = h; a2[rt][k] = l;
        }
    }
    argmin_body<RT, 64 / VS>(a1, a2, ehi, elo, nesqh, pk,
                             row0, (int)blockIdx.y * (256 / VS));
}

// si=5 fused: pool is identity (pn=32) -> split2 straight from frest.
// grid = (512, 2): RT=4, VS=2, each wave scans 32 tiles. (r10/r14-proven;
// VS=4, 2-deep pipe, and external-pool variants all regressed or tied.)
__global__ __launch_bounds__(256) void argmin5_fused(const float* __restrict__ frest,
                                                     const half_t* __restrict__ ehi,
                                                     const half_t* __restrict__ elo,
                                                     const float* __restrict__ nesqh,
                                                     u64_t* __restrict__ pk) {
    const int lane = threadIdx.x & 63;
    const int col  = lane & 15;
    const int quad = lane >> 4;
    const int row0 = blockIdx.x * 64;   // RT=4

    half8 a1[4], a2[4];
#pragma unroll
    for (int rt = 0; rt < 4; rt++) {
        int n = row0 + rt * 16 + col;               // row = (b*32+i)*32+j
        int b = n >> 10, i = (n >> 5) & 31, j = n & 31;
        const float* p = frest + ((((size_t)(b * CH + quad * 8)) * HH + i) * HH + j);
#pragma unroll
        for (int k = 0; k < 8; k++) {
            half_t h, l;
            split2(p[(size_t)k * (HH * HH)], &h, &l);   // c stride = 1024
            a1[rt][k] = h; a2[rt][k] = l;
        }
    }
    argmin_body<4, 32>(a1, a2, ehi, elo, nesqh, pk,
                       row0, (int)blockIdx.y * 128);
}

// ---------------------------------------------------------------------------
// bicubic weights, a=-0.75, half-pixel, edge clamp (matches ref _bicubic_mat)
__device__ inline void cubic_w(float xs, int pn, int* ix, float* w) {
    const float a = -0.75f;
    float xf = floorf(xs);
    int x0 = (int)xf;
    float t = xs - xf;
#pragma unroll
    for (int j = -1; j <= 2; j++) {
        float d = fabsf(t - (float)j);
        float ww;
        if (d < 1.0f)      ww = ((a + 2.0f) * d - (a + 3.0f)) * d * d + 1.0f;
        else if (d < 2.0f) ww = ((a * d - 5.0f * a) * d + 8.0f * a) * d - 4.0f * a;
        else               ww = 0.0f;
        int xi = x0 + j;
        xi = xi < 0 ? 0 : (xi > pn - 1 ? pn - 1 : xi);
        ix[j + 1] = xi;
        w[j + 1]  = ww;
    }
}

// ---------------------------------------------------------------------------
// FUSED upsample + Phi + residual: dst = src - (0.5*h + 0.5*(conv3x3(h)+bias))
// where h = bicubic_upsample(emb[winner_idx]) is computed in-register during
// LDS staging (bit-identical fma order to the old upsample_gather_kernel).
// grid: b(32) x yt(8) x co-quarter(4) = 1024 blocks (4 blocks/CU);
// block 256 = tx(32) x ty(8); thread: 4 rows x col tx x 1 co (co = coq*8+ty).
// PN = this scale's grid; PN_NEXT != 0 pools dst for the next scale into fp32
// partial sums (deterministic slots by yt, no atomics).
template <int PN, int PN_NEXT>
__global__ __launch_bounds__(256) void conv_fused_kernel(const u64_t* __restrict__ pk,
                                                         const float* __restrict__ emb,
                                                         const float* __restrict__ w,
                                                         const float* __restrict__ bias,
                                                         const float* __restrict__ src,
                                                         float* __restrict__ dst,
                                                         float* __restrict__ zp) {
    const int coq = blockIdx.x & 3;
    const int yt  = (blockIdx.x >> 2) & 7;
    const int b   = blockIdx.x >> 5;
    const int tx  = threadIdx.x & 31;
    const int ty  = threadIdx.x >> 5;     // 0..7
    const int y0  = yt * 4;

    __shared__ float wl[8 * 32 * 12];     // 12 KB
    __shared__ float til[16 * 6 * 34];    // 13.1 KB
    __shared__ int   idxg[PN * PN];       // winner indices for this b
    __shared__ int   riy[6][4];           // row bicubic windows (gy = y0-1..y0+4)
    __shared__ float rwy[6][4];
    __shared__ int   cix[34][4];          // col bicubic windows (gx = -1..32)
    __shared__ float cwx[34][4];

    {
        const float* wsrc = w + (size_t)coq * 8 * CH * 9;
        for (int i = threadIdx.x; i < 8 * 32 * 12; i += 256) {
            int k = i % 12;
            wl[i] = (k < 9) ? wsrc[(i / 12) * 9 + k] : 0.f;
        }
    }
    // winner index grid for this batch image
    for (int i = threadIdx.x; i < PN * PN; i += 256)
        idxg[i] = (int)(unsigned)(pk[b * PN * PN + i] & 0xFFFFFFFFull);
    // bicubic windows (rows by wave 0, cols by wave 1 -> parallel)
    const float scale = (float)PN / (float)HH;
    if (threadIdx.x < 6) {
        int r = threadIdx.x;
        int iy[4]; float wy[4];
        cubic_w(((float)(y0 - 1 + r) + 0.5f) * scale - 0.5f, PN, iy, wy);
#pragma unroll
        for (int a = 0; a < 4; a++) { riy[r][a] = iy[a]; rwy[r][a] = wy[a]; }
    }
    if (threadIdx.x >= 64 && threadIdx.x < 98) {
        int cl = threadIdx.x - 64;        // col 0..33, gx = cl-1
        int ix[4]; float wx[4];
        cubic_w(((float)(cl - 1) + 0.5f) * scale - 0.5f, PN, ix, wx);
#pragma unroll
        for (int a = 0; a < 4; a++) { cix[cl][a] = ix[a]; cwx[cl][a] = wx[a]; }
    }

    const int co = coq * 8 + ty;
    float acc[4];
#pragma unroll
    for (int ry = 0; ry < 4; ry++) acc[ry] = bias[co];
    float hcv[4];

    for (int cc = 0; cc < 2; cc++) {
        __syncthreads();
        // stage input: ci = cc*16 + 0..15, rows y0-1..y0+4, cols -1..32.
        // Each element is the bicubic upsample value (zero for pad).
        for (int i = threadIdx.x; i < 16 * 6 * 34; i += 256) {
            int col = i % 34;
            int row = (i / 34) % 6;
            int cil = i / 204;
            int gy = y0 - 1 + row;
            int gx = col - 1;
            float vv = 0.f;
            if ((unsigned)gy < 32u && (unsigned)gx < 32u) {
                const int c = cc * 16 + cil;
                float s = 0.f;
#pragma unroll
                for (int a = 0; a < 4; a++) {
                    float rsum = 0.f;
#pragma unroll
                    for (int b2 = 0; b2 < 4; b2++) {
                        int idx = idxg[riy[row][a] * PN + cix[col][b2]];
                        rsum = fmaf(emb[(size_t)idx * CH + c], cwx[col][b2], rsum);
                    }
                    s = fmaf(rsum, rwy[row][a], s);
                }
                vv = s;
            }
            til[i] = vv;
        }
        __syncthreads();

        // capture h at this thread's own output positions (channel co) from LDS
        if (cc == (co >> 4)) {
#pragma unroll
            for (int ry = 0; ry < 4; ry++)
                hcv[ry] = til[(co & 15) * 204 + (ry + 1) * 34 + (tx + 1)];
        }

        for (int cil = 0; cil < 16; cil++) {
            float in[6][3];
            const float* tp = &til[cil * 204];
#pragma unroll
            for (int rr2 = 0; rr2 < 6; rr2++)
#pragma unroll
                for (int dx = 0; dx < 3; dx++)
                    in[rr2][dx] = tp[rr2 * 34 + tx + dx];
            const float* wp = &wl[(ty * 32 + cc * 16 + cil) * 12];
            float4 wa = *(const float4*)wp;
            float4 wb = *(const float4*)(wp + 4);
            float  w8 = wp[8];
#pragma unroll
            for (int ry = 0; ry < 4; ry++) {
                float s = acc[ry];
                s = fmaf(in[ry + 0][0], wa.x, s);
                s = fmaf(in[ry + 0][1], wa.y, s);
                s = fmaf(in[ry + 0][2], wa.z, s);
                s = fmaf(in[ry + 1][0], wa.w, s);
                s = fmaf(in[ry + 1][1], wb.x, s);
                s = fmaf(in[ry + 1][2], wb.y, s);
                s = fmaf(in[ry + 2][0], wb.z, s);
                s = fmaf(in[ry + 2][1], wb.w, s);
                s = fmaf(in[ry + 2][2], w8,   s);
                acc[ry] = s;
            }
        }
    }

    float pv[4];
#pragma unroll
    for (int ry = 0; ry < 4; ry++) {
        size_t off = (((size_t)(b * CH + co)) * HH + (y0 + ry)) * HH + tx;
        float dv = src[off] - (0.5f * hcv[ry] + 0.5f * acc[ry]);
        dst[off] = dv;
        pv[ry] = dv;
    }

    if constexpr (PN_NEXT != 0) {
        constexpr int PSP  = 32 / PN_NEXT;               // 16/8/4/2
        constexpr int NWY  = (PSP == 2) ? 2 : 1;         // windows along y in this block
        constexpr int ZSTR = BS * PN_NEXT * PN_NEXT * CH;
        float wsum[NWY];
#pragma unroll
        for (int k = 0; k < NWY; k++) wsum[k] = 0.f;
#pragma unroll
        for (int ry = 0; ry < 4; ry++) wsum[(NWY == 2) ? (ry >> 1) : 0] += pv[ry];
        // reduce across tx groups of PSP lanes (tx = lane&31, tx is lane-minor)
#pragma unroll
        for (int m = 1; m < PSP; m <<= 1) {
#pragma unroll
            for (int k = 0; k < NWY; k++) wsum[k] += __shfl_xor(wsum[k], m, 64);
        }
        if ((tx & (PSP - 1)) == 0) {
            const int wx   = tx / PSP;
            const int slot = (PSP == 16) ? (yt & 3) : (PSP == 8) ? (yt & 1) : 0;
#pragma unroll
            for (int k = 0; k < NWY; k++) {
                const int wy = (PSP == 2) ? (yt * 2 + k) : (y0 / PSP);
                zp[(size_t)slot * ZSTR +
                   ((size_t)((b * PN_NEXT + wy) * PN_NEXT + wx)) * CH + co] = wsum[k];
            }
        }
    }
}

// ---------------------------------------------------------------------------
// fused bincount + perplexity + loss finalize (single block; LDS histogram
// over the 43680 packed winners, then entropy + lacc partial sum)
__global__ __launch_bounds__(256) void finalize_kernel(const u64_t* __restrict__ pk,
                                                       const float* __restrict__ laccp,
                                                       float* __restrict__ outs) {
    __shared__ float hist[VV];     // 16 KB
    __shared__ float sh[256];
    int t = threadIdx.x;
    for (int v = t; v < VV; v += 256) hist[v] = 0.f;
    __syncthreads();
    for (int i = t; i < NROWS_TOTAL; i += 256) {
        int idx = (int)(unsigned)(pk[i] & 0xFFFFFFFFull);
        atomicAdd(&hist[idx], 1.0f);
    }
    __syncthreads();
    // total = NROWS_TOTAL exactly (each row contributes one hit)
    const float tot = (float)NROWS_TOTAL;
    float ent = 0.f;
    for (int v = t; v < VV; v += 256) {
        float p = hist[v] / tot;
        ent += p * logf(p + 1e-10f);
    }
    sh[t] = ent;
    __syncthreads();
    for (int o = 128; o > 0; o >>= 1) {
        if (t < o) sh[t] += sh[t + o];
        __syncthreads();
    }
    float entT = sh[0];            // valid for all after the synced tree
    __syncthreads();
    float ls = 0.f;
    for (int i = t; i < 1024; i += 256) ls += laccp[i];
    sh[t] = ls;
    __syncthreads();
    for (int o = 128; o > 0; o >>= 1) {
        if (t < o) sh[t] += sh[t + o];
        __syncthreads();
    }
    if (t == 0) {
        // loss = SN*(1+BETA)*mean(f^2) = 7.5 * sumsq / 1048576  (f_hat stays 0)
        outs[0] = 7.5f * sh[0] * (1.0f / (float)FELEMS);
        outs[1] = expf(-entT);
    }
}

// ---------------------------------------------------------------------------
extern "C" void kernel_launch(void* const* d_in, const int* in_sizes, int n_in,
                              void* d_out, int out_size, void* d_ws, size_t ws_size,
                              hipStream_t stream) {
    const float* f   = (const float*)d_in[0];   // (32,32,32,32)
    const float* emb = (const float*)d_in[1];   // (4096,32)
    const float* phw = (const float*)d_in[2];   // (4,32,32,3,3)
    const float* phb = (const float*)d_in[3];   // (4,32)
    float* out = (float*)d_out;                 // f_hat (1048576) + loss + perplexity

    float* ws      = (float*)d_ws;
    float* laccp   = ws + 4096;                       // [4096, 5120) partials
    u64_t* pkbase  = (u64_t*)(ws + 8448);             // 43680 u64 -> [8448, 95808)
    float* frest   = ws + 95808;                      // [95808, 1144384)
    half_t* zhi    = (half_t*)(ws + 1144384);         // si=0 z-split (1024 used)
    half_t* zlo    = (half_t*)(ws + 1275456);
    float* nesqh   = ws + 1537600;                    // [1537600, 1541696)
    half_t* ehi    = (half_t*)(ws + 2590272);         // 131072 halves = 65536 f
    half_t* elo    = (half_t*)(ws + 2655808);         // ends 2721344
    float* zp      = ws + 2721344;                    // 262144 f -> ends 2983488 (11.9 MB)

    // prep: emb split + nesqh + zero f_hat + pk=+inf + pool si=0 + lacc
    prep_kernel<<<1024, 256, 0, stream>>>(f, emb, ehi, elo, nesqh, laccp,
                                          zhi, zlo, pkbase, out);

    const int pkoff[6] = {0, 32, 160, 672, 2720, 10912};
    const size_t WSTR = (size_t)CH * CH * 9;          // 9216 per phi

    // si=0 (pn=1, sel=0): argmin from prep's z-split; conv pools for pn=2 (4 slots)
    argmin_stage<1, 16><<<dim3(2, 16), 256, 0, stream>>>(zhi, zlo, ehi, elo, nesqh,
                                                         pkbase + pkoff[0]);
    conv_fused_kernel<1, 2><<<1024, 256, 0, stream>>>(pkbase + pkoff[0], emb,
                                                      phw + 0 * WSTR, phb + 0 * CH,
                                                      f, frest, zp);

    // si=1 (pn=2, sel=0): z from 4 fp32 partials; conv pools for pn=4 (2 slots)
    argmin_zp<1, 16, 4, 2><<<dim3(8, 16), 256, 0, stream>>>(zp, ehi, elo, nesqh,
                                                            pkbase + pkoff[1]);
    conv_fused_kernel<2, 4><<<1024, 256, 0, stream>>>(pkbase + pkoff[1], emb,
                                                      phw + 0 * WSTR, phb + 0 * CH,
                                                      frest, frest, zp);

    // si=2 (pn=4, sel=1): z from 2 partials; conv pools for pn=8 (1 slot)
    argmin_zp<1, 16, 2, 4><<<dim3(32, 16), 256, 0, stream>>>(zp, ehi, elo, nesqh,
                                                             pkbase + pkoff[2]);
    conv_fused_kernel<4, 8><<<1024, 256, 0, stream>>>(pkbase + pkoff[2], emb,
                                                      phw + 1 * WSTR, phb + 1 * CH,
                                                      frest, frest, zp);

    // si=3 (pn=8, sel=2): z from 1 partial; conv pools for pn=16 (1 slot)
    argmin_zp<1, 8, 1, 8><<<dim3(128, 8), 256, 0, stream>>>(zp, ehi, elo, nesqh,
                                                            pkbase + pkoff[3]);
    conv_fused_kernel<8, 16><<<1024, 256, 0, stream>>>(pkbase + pkoff[3], emb,
                                                       phw + 2 * WSTR, phb + 2 * CH,
                                                       frest, frest, zp);

    // si=4 (pn=16, sel=3): z from 1 partial; conv has no pooling (si=5 reads frest)
    argmin_zp<2, 4, 1, 16><<<dim3(256, 4), 256, 0, stream>>>(zp, ehi, elo, nesqh,
                                                             pkbase + pkoff[4]);
    conv_fused_kernel<16, 0><<<1024, 256, 0, stream>>>(pkbase + pkoff[4], emb,
                                                       phw + 3 * WSTR, phb + 3 * CH,
                                                       frest, frest, nullptr);

    // si=5 (pn=32, sel=3): fused identity-pool argmin straight from frest
    argmin5_fused<<<dim3(512, 2), 256, 0, stream>>>(frest, ehi, elo, nesqh,
                                                    pkbase + pkoff[5]);

    finalize_kernel<<<1, 256, 0, stream>>>(pkbase, laccp, out + (out_size - 2));
}

// Round 3
// 384.563 us; speedup vs baseline: 2.0479x; 2.0479x over previous
//
#include <hip/hip_runtime.h>
#include <math.h>
#include <float.h>

// Problem constants (B=32, C=32, H=W=32, V=4096)
#define BS    32
#define CH    32
#define HH    32
#define VV    4096
#define FELEMS (BS*CH*HH*HH)   // 1048576
#define NROWS_TOTAL 43680      // sum over scales of B*pn*pn

typedef unsigned short ushort_t;
typedef unsigned long long u64_t;
typedef _Float16 half_t;
typedef __attribute__((ext_vector_type(8))) _Float16 half8;
typedef __attribute__((ext_vector_type(4))) float floatx4;

// 2-way fp16 split: x ~= h + l, residual <= 2^-22 |x|
__device__ inline void split2(float x, half_t* h, half_t* l) {
    half_t hh = (half_t)x;
    float r = x - (float)hh;
    *h = hh;
    *l = (half_t)r;
}

// fp32 -> sortable-descending key32 (bigger score => smaller key)
__device__ inline unsigned score_key32(float s) {
    unsigned u = __builtin_bit_cast(unsigned, s);
    unsigned m = (u & 0x80000000u) ? ~u : (u | 0x80000000u);  // monotone asc
    return ~m;                                                 // desc
}

// ---------------------------------------------------------------------------
// prep (grid 1024x256): emb fp16-split + nesqh, zero f_hat output,
// init pk keys to +inf, AND pool si=0 (pn=1: block = (b,c) pair, mean over
// 1024 px -> zhi/zlo) with per-block sumsq partials (deterministic, no
// atomics, no zero-init) for the loss.
__global__ __launch_bounds__(256) void prep_kernel(const float* __restrict__ f,
                                                   const float* __restrict__ emb,
                                                   half_t* __restrict__ ehi,
                                                   half_t* __restrict__ elo,
                                                   float* __restrict__ nesqh,
                                                   float* __restrict__ laccp,
                                                   half_t* __restrict__ zhi,
                                                   half_t* __restrict__ zlo,
                                                   u64_t* __restrict__ pk,
                                                   float* __restrict__ dout) {
    int gid = blockIdx.x * 256 + threadIdx.x;      // 262144 threads
    float4 z4 = {0.f, 0.f, 0.f, 0.f};
    *(float4*)(dout + (size_t)gid * 4) = z4;
    if (gid < NROWS_TOTAL) pk[gid] = ~0ull;        // +inf keys
    if (gid < VV) {
        int v = gid;
        const float* ep = emb + (size_t)v * CH;
        float s = 0.f;
        half_t h[CH], l[CH];
#pragma unroll
        for (int i = 0; i < CH; i++) {
            float e = ep[i];
            s = fmaf(e, e, s);
            split2(e, &h[i], &l[i]);
        }
        nesqh[v] = -0.5f * s;
#pragma unroll
        for (int q = 0; q < 4; q++) {
            half8 H, L;
#pragma unroll
            for (int k = 0; k < 8; k++) {
                H[k] = h[q * 8 + k];
                L[k] = l[q * 8 + k];
            }
            *(half8*)(ehi + (size_t)v * CH + q * 8) = H;
            *(half8*)(elo + (size_t)v * CH + q * 8) = L;
        }
    }

    // pool si=0: pair = blockIdx.x = b*32 + c; base = f + pair*1024
    const int pair = blockIdx.x;
    const float* base = f + (size_t)pair * 1024;
    float s = 0.f, s2 = 0.f;
    for (int p = threadIdx.x; p < 1024; p += 256) {
        float v = base[p];
        s += v;
        s2 = fmaf(v, v, s2);
    }
    __shared__ float sh[256], sh2[256];
    sh[threadIdx.x] = s;
    sh2[threadIdx.x] = s2;
    __syncthreads();
    for (int o = 128; o > 0; o >>= 1) {
        if (threadIdx.x < o) {
            sh[threadIdx.x]  += sh[threadIdx.x + o];
            sh2[threadIdx.x] += sh2[threadIdx.x + o];
        }
        __syncthreads();
    }
    if (threadIdx.x == 0) {
        split2(sh[0] * (1.0f / 1024.0f), &zhi[pair], &zlo[pair]);
        laccp[pair] = sh2[0];      // deterministic partial, summed in finalize
    }
}

// ---------------------------------------------------------------------------
// 3-MFMA fp16 score chain for one 16-row group vs one 16-code tile
// score = z.e - 0.5|e|^2 = ah.bh + ah.bl + al.bh  (al.bl <= 2^-22 dropped)
__device__ inline floatx4 score_chain(half8 ah, half8 al,
                                      half8 bh, half8 bl, floatx4 ehv) {
    floatx4 acc;
    acc = __builtin_amdgcn_mfma_f32_16x16x32_f16(ah, bh, ehv, 0, 0, 0);
    acc = __builtin_amdgcn_mfma_f32_16x16x32_f16(ah, bl, acc, 0, 0, 0);
    acc = __builtin_amdgcn_mfma_f32_16x16x32_f16(al, bh, acc, 0, 0, 0);
    return acc;
}

__device__ inline void sel4(const floatx4& acc, int v, float* best, int* bidx) {
#pragma unroll
    for (int r = 0; r < 4; r++) {
        // strict >: lane-local scan is increasing v -> keeps lowest v on tie
        if (acc[r] > best[r]) { best[r] = acc[r]; bidx[r] = v; }
    }
}

// argmin core (1-deep prefetch — the proven fastest of four structural
// variants: 2-deep pipe, VS ladders, pooled-stage all regressed or tied).
// Wave wv scans TPW v-tiles from t0+wv*TPW over RT 16-row tiles.
// Deferred-select interleave (RT>=2). Winner per row merged cross-block via
// packed-key atomicMin (max score, lowest idx on tie == jnp.argmin).
template <int RT, int TPW>
__device__ inline void argmin_body(const half8* a1, const half8* a2,
                                   const half_t* __restrict__ ehi,
                                   const half_t* __restrict__ elo,
                                   const float* __restrict__ nesqh,
                                   u64_t* __restrict__ pk, int row0, int t0) {
    const int tid  = threadIdx.x;
    const int wv   = tid >> 6;
    const int lane = tid & 63;
    const int col  = lane & 15;
    const int quad = lane >> 4;

    float best[RT][4];
    int   bidx[RT][4];
#pragma unroll
    for (int rt = 0; rt < RT; rt++)
#pragma unroll
        for (int r = 0; r < 4; r++) { best[rt][r] = -FLT_MAX; bidx[rt][r] = 0; }

    int t = t0 + wv * TPW;
    const int tend = t + TPW;

    // prefetch tile t
    size_t eoff = ((size_t)((t << 4) + col) << 5) + (quad << 3);
    half8 nb1 = *(const half8*)(ehi + eoff);
    half8 nb2 = *(const half8*)(elo + eoff);
    float neh = nesqh[(t << 4) + col];

    floatx4 acc[RT];
    int vprev = 0;
    if (RT > 1) acc[RT - 1] = floatx4{-FLT_MAX, -FLT_MAX, -FLT_MAX, -FLT_MAX};

    for (; t < tend; t++) {
        const half8 b1 = nb1, b2 = nb2;
        const floatx4 ehv = {neh, neh, neh, neh};
        const int vcur = (t << 4) + col;
        // prefetch t+1 (clamped) before consuming current
        const int tn = (t + 1 < tend) ? (t + 1) : t;
        const size_t eoff2 = ((size_t)((tn << 4) + col) << 5) + (quad << 3);
        nb1 = *(const half8*)(ehi + eoff2);
        nb2 = *(const half8*)(elo + eoff2);
        neh = nesqh[(tn << 4) + col];

        if (RT == 1) {
            acc[0] = score_chain(a1[0], a2[0], b1, b2, ehv);
            sel4(acc[0], vcur, best[0], bidx[0]);
        } else {
            acc[0] = score_chain(a1[0], a2[0], b1, b2, ehv);
            sel4(acc[RT - 1], vprev, best[RT - 1], bidx[RT - 1]);  // deferred
#pragma unroll
            for (int rt = 1; rt < RT; rt++) {
                acc[rt] = score_chain(a1[rt], a2[rt], b1, b2, ehv);
                sel4(acc[rt - 1], vcur, best[rt - 1], bidx[rt - 1]);
            }
            vprev = vcur;
        }
    }
    if (RT > 1) sel4(acc[RT - 1], vprev, best[RT - 1], bidx[RT - 1]);

    // reduce across the 16 cols (v within tile) of each quad group
#pragma unroll
    for (int m = 1; m < 16; m <<= 1) {
#pragma unroll
        for (int rt = 0; rt < RT; rt++)
#pragma unroll
            for (int r = 0; r < 4; r++) {
                float s2 = __shfl_xor(best[rt][r], m, 64);
                int   v2 = __shfl_xor(bidx[rt][r], m, 64);
                if (s2 > best[rt][r] ||
                    (s2 == best[rt][r] && v2 < bidx[rt][r])) {
                    best[rt][r] = s2; bidx[rt][r] = v2;
                }
            }
    }

    __shared__ float sbs[4 * RT * 16];
    __shared__ int   sbi[4 * RT * 16];
    if (col == 0) {
#pragma unroll
        for (int rt = 0; rt < RT; rt++)
#pragma unroll
            for (int r = 0; r < 4; r++) {
                int row = rt * 16 + (quad << 2) + r;
                sbs[wv * RT * 16 + row] = best[rt][r];
                sbi[wv * RT * 16 + row] = bidx[rt][r];
            }
    }
    __syncthreads();
    if (tid < RT * 16) {
        float s = sbs[tid];
        int   v = sbi[tid];
        for (int w = 1; w < 4; w++) {
            float s2 = sbs[w * RT * 16 + tid];
            int   v2 = sbi[w * RT * 16 + tid];
            if (s2 > s || (s2 == s && v2 < v)) { s = s2; v = v2; }
        }
        u64_t key = ((u64_t)score_key32(s) << 32) | (unsigned)v;
        atomicMin(pk + row0 + tid, key);
    }
}

// generic stage: z-splits from memory (si=0 only now). grid = (nRowBlocks, VS)
template <int RT, int VS>
__global__ __launch_bounds__(256) void argmin_stage(const half_t* __restrict__ zhi,
                                                    const half_t* __restrict__ zlo,
                                                    const half_t* __restrict__ ehi,
                                                    const half_t* __restrict__ elo,
                                                    const float* __restrict__ nesqh,
                                                    u64_t* __restrict__ pk) {
    const int lane = threadIdx.x & 63;
    const int col  = lane & 15;
    const int quad = lane >> 4;
    const int row0 = blockIdx.x * (16 * RT);

    half8 a1[RT], a2[RT];
#pragma unroll
    for (int rt = 0; rt < RT; rt++) {
        size_t off = ((size_t)(row0 + rt * 16 + col) << 5) + (quad << 3);
        a1[rt] = *(const half8*)(zhi + off);
        a2[rt] = *(const half8*)(zlo + off);
    }
    argmin_body<RT, 64 / VS>(a1, a2, ehi, elo, nesqh, pk,
                             row0, (int)blockIdx.y * (256 / VS));
}

// zp stage (si=1..4): pooled z comes as NSLOT fp32 partial sums written by the
// previous conv's epilogue. Sum partials in fixed slot order, scale by the
// exact power-of-two 1/ps'^2, split2 in-register. Row-coalesced loads
// (wave reads 16 contiguous 128B rows).
template <int RT, int VS, int NSLOT, int PN>
__global__ __launch_bounds__(256) void argmin_zp(const float* __restrict__ zp,
                                                 const half_t* __restrict__ ehi,
                                                 const half_t* __restrict__ elo,
                                                 const float* __restrict__ nesqh,
                                                 u64_t* __restrict__ pk) {
    const int lane = threadIdx.x & 63;
    const int col  = lane & 15;
    const int quad = lane >> 4;
    const int row0 = blockIdx.x * (16 * RT);
    constexpr int ZSTR = BS * PN * PN * CH;
    constexpr int PSP  = 32 / PN;
    const float scale = 1.0f / (float)(PSP * PSP);

    half8 a1[RT], a2[RT];
#pragma unroll
    for (int rt = 0; rt < RT; rt++) {
        const float* p = zp + (size_t)(row0 + rt * 16 + col) * CH + (quad << 3);
        float4 v0 = *(const float4*)p;
        float4 v1 = *(const float4*)(p + 4);
#pragma unroll
        for (int sl = 1; sl < NSLOT; sl++) {
            float4 u0 = *(const float4*)(p + (size_t)sl * ZSTR);
            float4 u1 = *(const float4*)(p + (size_t)sl * ZSTR + 4);
            v0.x += u0.x; v0.y += u0.y; v0.z += u0.z; v0.w += u0.w;
            v1.x += u1.x; v1.y += u1.y; v1.z += u1.z; v1.w += u1.w;
        }
        float s[8] = {v0.x, v0.y, v0.z, v0.w, v1.x, v1.y, v1.z, v1.w};
#pragma unroll
        for (int k = 0; k < 8; k++) {
            half_t h, l;
            split2(s[k] * scale, &h, &l);
            a1[rt][k] = h; a2[rt][k] = l;
        }
    }
    argmin_body<RT, 64 / VS>(a1, a2, ehi, elo, nesqh, pk,
                             row0, (int)blockIdx.y * (256 / VS));
}

// si=5 fused: pool is identity (pn=32) -> split2 straight from frest.
// grid = (512, 2): RT=4, VS=2, each wave scans 32 tiles. (r10/r14-proven;
// VS=4, 2-deep pipe, and external-pool variants all regressed or tied.)
__global__ __launch_bounds__(256) void argmin5_fused(const float* __restrict__ frest,
                                                     const half_t* __restrict__ ehi,
                                                     const half_t* __restrict__ elo,
                                                     const float* __restrict__ nesqh,
                                                     u64_t* __restrict__ pk) {
    const int lane = threadIdx.x & 63;
    const int col  = lane & 15;
    const int quad = lane >> 4;
    const int row0 = blockIdx.x * 64;   // RT=4

    half8 a1[4], a2[4];
#pragma unroll
    for (int rt = 0; rt < 4; rt++) {
        int n = row0 + rt * 16 + col;               // row = (b*32+i)*32+j
        int b = n >> 10, i = (n >> 5) & 31, j = n & 31;
        const float* p = frest + ((((size_t)(b * CH + quad * 8)) * HH + i) * HH + j);
#pragma unroll
        for (int k = 0; k < 8; k++) {
            half_t h, l;
            split2(p[(size_t)k * (HH * HH)], &h, &l);   // c stride = 1024
            a1[rt][k] = h; a2[rt][k] = l;
        }
    }
    argmin_body<4, 32>(a1, a2, ehi, elo, nesqh, pk,
                       row0, (int)blockIdx.y * 128);
}

// ---------------------------------------------------------------------------
// bicubic weights, a=-0.75, half-pixel, edge clamp (matches ref _bicubic_mat)
__device__ inline void cubic_w(float xs, int pn, int* ix, float* w) {
    const float a = -0.75f;
    float xf = floorf(xs);
    int x0 = (int)xf;
    float t = xs - xf;
#pragma unroll
    for (int j = -1; j <= 2; j++) {
        float d = fabsf(t - (float)j);
        float ww;
        if (d < 1.0f)      ww = ((a + 2.0f) * d - (a + 3.0f)) * d * d + 1.0f;
        else if (d < 2.0f) ww = ((a * d - 5.0f * a) * d + 8.0f * a) * d - 4.0f * a;
        else               ww = 0.0f;
        int xi = x0 + j;
        xi = xi < 0 ? 0 : (xi > pn - 1 ? pn - 1 : xi);
        ix[j + 1] = xi;
        w[j + 1]  = ww;
    }
}

// ---------------------------------------------------------------------------
// FUSED upsample + Phi + residual: dst = src - (0.5*h + 0.5*(conv3x3(h)+bias))
// h = bicubic_upsample(emb[winner_idx]) computed during LDS staging with
// bit-identical fma order to the old upsample_gather_kernel. FIX vs r2: the
// needed emb rows (iy-band <=8 x PN cols x 16 ch) are first gathered into LDS
// with coalesced loads (~8 loads/thread), and the 16 bicubic taps read LDS —
// removes the 400 serial scattered global gathers/thread that made r2
// latency-bound (200us/conv @ VALUBusy 14%).
// grid: b(32) x yt(8) x co-quarter(4) = 1024 blocks; block 256 = tx(32) x ty(8).
// PN_NEXT != 0 pools dst for the next scale into fp32 partial-sum slots.
template <int PN, int PN_NEXT>
__global__ __launch_bounds__(256) void conv_fused_kernel(const u64_t* __restrict__ pk,
                                                         const float* __restrict__ emb,
                                                         const float* __restrict__ w,
                                                         const float* __restrict__ bias,
                                                         const float* __restrict__ src,
                                                         float* __restrict__ dst,
                                                         float* __restrict__ zp) {
    constexpr int IYB = (PN <= 4) ? PN : 8;   // cached iy-band height (tap span <=7)
    const int coq = blockIdx.x & 3;
    const int yt  = (blockIdx.x >> 2) & 7;
    const int b   = blockIdx.x >> 5;
    const int tx  = threadIdx.x & 31;
    const int ty  = threadIdx.x >> 5;     // 0..7
    const int y0  = yt * 4;

    __shared__ float wl[8 * 32 * 12];     // 12 KB
    __shared__ float til[16 * 6 * 34];    // 13.1 KB
    __shared__ int   idxg[PN * PN];       // winner indices for this b
    __shared__ int   riy[6][4];           // row bicubic windows (gy = y0-1..y0+4)
    __shared__ float rwy[6][4];
    __shared__ int   cix[34][4];          // col bicubic windows (gx = -1..32)
    __shared__ float cwx[34][4];
    // emb-row cache: [ch 16][iy band][ix + pad] — ch-major so tap reads
    // (lanes differ in ix) are bank-conflict-free; +1 pad de-conflicts writes.
    __shared__ float cache[16][IYB][PN + 1];

    {
        const float* wsrc = w + (size_t)coq * 8 * CH * 9;
        for (int i = threadIdx.x; i < 8 * 32 * 12; i += 256) {
            int k = i % 12;
            wl[i] = (k < 9) ? wsrc[(i / 12) * 9 + k] : 0.f;
        }
    }
    // winner index grid for this batch image
    for (int i = threadIdx.x; i < PN * PN; i += 256)
        idxg[i] = (int)(unsigned)(pk[b * PN * PN + i] & 0xFFFFFFFFull);
    // bicubic windows (rows by wave 0, cols by wave 1 -> parallel)
    const float scale = (float)PN / (float)HH;
    if (threadIdx.x < 6) {
        int r = threadIdx.x;
        int iy[4]; float wy[4];
        cubic_w(((float)(y0 - 1 + r) + 0.5f) * scale - 0.5f, PN, iy, wy);
#pragma unroll
        for (int a = 0; a < 4; a++) { riy[r][a] = iy[a]; rwy[r][a] = wy[a]; }
    }
    if (threadIdx.x >= 64 && threadIdx.x < 98) {
        int cl = threadIdx.x - 64;        // col 0..33, gx = cl-1
        int ix[4]; float wx[4];
        cubic_w(((float)(cl - 1) + 0.5f) * scale - 0.5f, PN, ix, wx);
#pragma unroll
        for (int a = 0; a < 4; a++) { cix[cl][a] = ix[a]; cwx[cl][a] = wx[a]; }
    }

    // iy-band start: covers all clamped taps of gy in [y0-1, y0+4].
    // Computed redundantly per-thread (deterministic). For PN<=4 band = grid.
    int iy_lo = 0;
    if (PN > 4) {
        int lo = (int)floorf(((float)(y0 - 1) + 0.5f) * scale - 0.5f) - 1;
        if (lo < 0) lo = 0;
        if (lo > PN - IYB) lo = PN - IYB;
        iy_lo = lo;
    }

    const int co = coq * 8 + ty;
    float acc[4];
#pragma unroll
    for (int ry = 0; ry < 4; ry++) acc[ry] = bias[co];
    float hcv[4];

    for (int cc = 0; cc < 2; cc++) {
        __syncthreads();                  // idxg/windows ready (iter 0); til free
        // gather emb rows for this cc half into cache (coalesced: 16
        // consecutive ch floats per cell)
        for (int i = threadIdx.x; i < IYB * PN * 16; i += 256) {
            int cil  = i & 15;
            int cell = i >> 4;
            int ix   = cell % PN;
            int iyb  = cell / PN;
            int idx  = idxg[(iy_lo + iyb) * PN + ix];
            cache[cil][iyb][ix] = emb[(size_t)idx * CH + cc * 16 + cil];
        }
        __syncthreads();
        // stage input: ci = cc*16 + 0..15, rows y0-1..y0+4, cols -1..32.
        // Each element is the bicubic upsample value (zero for pad), taps
        // read from the LDS cache (bit-identical values & fma order).
        for (int i = threadIdx.x; i < 16 * 6 * 34; i += 256) {
            int col = i % 34;
            int row = (i / 34) % 6;
            int cil = i / 204;
            int gy = y0 - 1 + row;
            int gx = col - 1;
            float vv = 0.f;
            if ((unsigned)gy < 32u && (unsigned)gx < 32u) {
                float s = 0.f;
#pragma unroll
                for (int a = 0; a < 4; a++) {
                    const int iyb = riy[row][a] - iy_lo;
                    float rsum = 0.f;
#pragma unroll
                    for (int b2 = 0; b2 < 4; b2++) {
                        rsum = fmaf(cache[cil][iyb][cix[col][b2]],
                                    cwx[col][b2], rsum);
                    }
                    s = fmaf(rsum, rwy[row][a], s);
                }
                vv = s;
            }
            til[i] = vv;
        }
        __syncthreads();

        // capture h at this thread's own output positions (channel co) from LDS
        if (cc == (co >> 4)) {
#pragma unroll
            for (int ry = 0; ry < 4; ry++)
                hcv[ry] = til[(co & 15) * 204 + (ry + 1) * 34 + (tx + 1)];
        }

        for (int cil = 0; cil < 16; cil++) {
            float in[6][3];
            const float* tp = &til[cil * 204];
#pragma unroll
            for (int rr2 = 0; rr2 < 6; rr2++)
#pragma unroll
                for (int dx = 0; dx < 3; dx++)
                    in[rr2][dx] = tp[rr2 * 34 + tx + dx];
            const float* wp = &wl[(ty * 32 + cc * 16 + cil) * 12];
            float4 wa = *(const float4*)wp;
            float4 wb = *(const float4*)(wp + 4);
            float  w8 = wp[8];
#pragma unroll
            for (int ry = 0; ry < 4; ry++) {
                float s = acc[ry];
                s = fmaf(in[ry + 0][0], wa.x, s);
                s = fmaf(in[ry + 0][1], wa.y, s);
                s = fmaf(in[ry + 0][2], wa.z, s);
                s = fmaf(in[ry + 1][0], wa.w, s);
                s = fmaf(in[ry + 1][1], wb.x, s);
                s = fmaf(in[ry + 1][2], wb.y, s);
                s = fmaf(in[ry + 2][0], wb.z, s);
                s = fmaf(in[ry + 2][1], wb.w, s);
                s = fmaf(in[ry + 2][2], w8,   s);
                acc[ry] = s;
            }
        }
    }

    float pv[4];
#pragma unroll
    for (int ry = 0; ry < 4; ry++) {
        size_t off = (((size_t)(b * CH + co)) * HH + (y0 + ry)) * HH + tx;
        float dv = src[off] - (0.5f * hcv[ry] + 0.5f * acc[ry]);
        dst[off] = dv;
        pv[ry] = dv;
    }

    if constexpr (PN_NEXT != 0) {
        constexpr int PSP  = 32 / PN_NEXT;               // 16/8/4/2
        constexpr int NWY  = (PSP == 2) ? 2 : 1;         // windows along y in this block
        constexpr int ZSTR = BS * PN_NEXT * PN_NEXT * CH;
        float wsum[NWY];
#pragma unroll
        for (int k = 0; k < NWY; k++) wsum[k] = 0.f;
#pragma unroll
        for (int ry = 0; ry < 4; ry++) wsum[(NWY == 2) ? (ry >> 1) : 0] += pv[ry];
        // reduce across tx groups of PSP lanes (tx = lane&31, tx is lane-minor)
#pragma unroll
        for (int m = 1; m < PSP; m <<= 1) {
#pragma unroll
            for (int k = 0; k < NWY; k++) wsum[k] += __shfl_xor(wsum[k], m, 64);
        }
        if ((tx & (PSP - 1)) == 0) {
            const int wx   = tx / PSP;
            const int slot = (PSP == 16) ? (yt & 3) : (PSP == 8) ? (yt & 1) : 0;
#pragma unroll
            for (int k = 0; k < NWY; k++) {
                const int wy = (PSP == 2) ? (yt * 2 + k) : (y0 / PSP);
                zp[(size_t)slot * ZSTR +
                   ((size_t)((b * PN_NEXT + wy) * PN_NEXT + wx)) * CH + co] = wsum[k];
            }
        }
    }
}

// ---------------------------------------------------------------------------
// fused bincount + perplexity + loss finalize (single block; LDS histogram
// over the 43680 packed winners, then entropy + lacc partial sum)
__global__ __launch_bounds__(256) void finalize_kernel(const u64_t* __restrict__ pk,
                                                       const float* __restrict__ laccp,
                                                       float* __restrict__ outs) {
    __shared__ float hist[VV];     // 16 KB
    __shared__ float sh[256];
    int t = threadIdx.x;
    for (int v = t; v < VV; v += 256) hist[v] = 0.f;
    __syncthreads();
    for (int i = t; i < NROWS_TOTAL; i += 256) {
        int idx = (int)(unsigned)(pk[i] & 0xFFFFFFFFull);
        atomicAdd(&hist[idx], 1.0f);
    }
    __syncthreads();
    // total = NROWS_TOTAL exactly (each row contributes one hit)
    const float tot = (float)NROWS_TOTAL;
    float ent = 0.f;
    for (int v = t; v < VV; v += 256) {
        float p = hist[v] / tot;
        ent += p * logf(p + 1e-10f);
    }
    sh[t] = ent;
    __syncthreads();
    for (int o = 128; o > 0; o >>= 1) {
        if (t < o) sh[t] += sh[t + o];
        __syncthreads();
    }
    float entT = sh[0];            // valid for all after the synced tree
    __syncthreads();
    float ls = 0.f;
    for (int i = t; i < 1024; i += 256) ls += laccp[i];
    sh[t] = ls;
    __syncthreads();
    for (int o = 128; o > 0; o >>= 1) {
        if (t < o) sh[t] += sh[t + o];
        __syncthreads();
    }
    if (t == 0) {
        // loss = SN*(1+BETA)*mean(f^2) = 7.5 * sumsq / 1048576  (f_hat stays 0)
        outs[0] = 7.5f * sh[0] * (1.0f / (float)FELEMS);
        outs[1] = expf(-entT);
    }
}

// ---------------------------------------------------------------------------
extern "C" void kernel_launch(void* const* d_in, const int* in_sizes, int n_in,
                              void* d_out, int out_size, void* d_ws, size_t ws_size,
                              hipStream_t stream) {
    const float* f   = (const float*)d_in[0];   // (32,32,32,32)
    const float* emb = (const float*)d_in[1];   // (4096,32)
    const float* phw = (const float*)d_in[2];   // (4,32,32,3,3)
    const float* phb = (const float*)d_in[3];   // (4,32)
    float* out = (float*)d_out;                 // f_hat (1048576) + loss + perplexity

    float* ws      = (float*)d_ws;
    float* laccp   = ws + 4096;                       // [4096, 5120) partials
    u64_t* pkbase  = (u64_t*)(ws + 8448);             // 43680 u64 -> [8448, 95808)
    float* frest   = ws + 95808;                      // [95808, 1144384)
    half_t* zhi    = (half_t*)(ws + 1144384);         // si=0 z-split (1024 used)
    half_t* zlo    = (half_t*)(ws + 1275456);
    float* nesqh   = ws + 1537600;                    // [1537600, 1541696)
    half_t* ehi    = (half_t*)(ws + 2590272);         // 131072 halves = 65536 f
    half_t* elo    = (half_t*)(ws + 2655808);         // ends 2721344
    float* zp      = ws + 2721344;                    // 262144 f -> ends 2983488 (11.9 MB)

    // prep: emb split + nesqh + zero f_hat + pk=+inf + pool si=0 + lacc
    prep_kernel<<<1024, 256, 0, stream>>>(f, emb, ehi, elo, nesqh, laccp,
                                          zhi, zlo, pkbase, out);

    const int pkoff[6] = {0, 32, 160, 672, 2720, 10912};
    const size_t WSTR = (size_t)CH * CH * 9;          // 9216 per phi

    // si=0 (pn=1, sel=0): argmin from prep's z-split; conv pools for pn=2 (4 slots)
    argmin_stage<1, 16><<<dim3(2, 16), 256, 0, stream>>>(zhi, zlo, ehi, elo, nesqh,
                                                         pkbase + pkoff[0]);
    conv_fused_kernel<1, 2><<<1024, 256, 0, stream>>>(pkbase + pkoff[0], emb,
                                                      phw + 0 * WSTR, phb + 0 * CH,
                                                      f, frest, zp);

    // si=1 (pn=2, sel=0): z from 4 fp32 partials; conv pools for pn=4 (2 slots)
    argmin_zp<1, 16, 4, 2><<<dim3(8, 16), 256, 0, stream>>>(zp, ehi, elo, nesqh,
                                                            pkbase + pkoff[1]);
    conv_fused_kernel<2, 4><<<1024, 256, 0, stream>>>(pkbase + pkoff[1], emb,
                                                      phw + 0 * WSTR, phb + 0 * CH,
                                                      frest, frest, zp);

    // si=2 (pn=4, sel=1): z from 2 partials; conv pools for pn=8 (1 slot)
    argmin_zp<1, 16, 2, 4><<<dim3(32, 16), 256, 0, stream>>>(zp, ehi, elo, nesqh,
                                                             pkbase + pkoff[2]);
    conv_fused_kernel<4, 8><<<1024, 256, 0, stream>>>(pkbase + pkoff[2], emb,
                                                      phw + 1 * WSTR, phb + 1 * CH,
                                                      frest, frest, zp);

    // si=3 (pn=8, sel=2): z from 1 partial; conv pools for pn=16 (1 slot)
    argmin_zp<1, 8, 1, 8><<<dim3(128, 8), 256, 0, stream>>>(zp, ehi, elo, nesqh,
                                                            pkbase + pkoff[3]);
    conv_fused_kernel<8, 16><<<1024, 256, 0, stream>>>(pkbase + pkoff[3], emb,
                                                       phw + 2 * WSTR, phb + 2 * CH,
                                                       frest, frest, zp);

    // si=4 (pn=16, sel=3): z from 1 partial; conv has no pooling (si=5 reads frest)
    argmin_zp<2, 4, 1, 16><<<dim3(256, 4), 256, 0, stream>>>(zp, ehi, elo, nesqh,
                                                             pkbase + pkoff[4]);
    conv_fused_kernel<16, 0><<<1024, 256, 0, stream>>>(pkbase + pkoff[4], emb,
                                                       phw + 3 * WSTR, phb + 3 * CH,
                                                       frest, frest, nullptr);

    // si=5 (pn=32, sel=3): fused identity-pool argmin straight from frest
    argmin5_fused<<<dim3(512, 2), 256, 0, stream>>>(frest, ehi, elo, nesqh,
                                                    pkbase + pkoff[5]);

    finalize_kernel<<<1, 256, 0, stream>>>(pkbase, laccp, out + (out_size - 2));
}

// Round 4
// 345.130 us; speedup vs baseline: 2.2818x; 1.1143x over previous
//
#include <hip/hip_runtime.h>
#include <math.h>
#include <float.h>

// Problem constants (B=32, C=32, H=W=32, V=4096)
#define BS    32
#define CH    32
#define HH    32
#define VV    4096
#define FELEMS (BS*CH*HH*HH)   // 1048576
#define NROWS_TOTAL 43680      // sum over scales of B*pn*pn

typedef unsigned short ushort_t;
typedef unsigned long long u64_t;
typedef _Float16 half_t;
typedef __attribute__((ext_vector_type(8))) _Float16 half8;
typedef __attribute__((ext_vector_type(4))) float floatx4;

// 2-way fp16 split: x ~= h + l, residual <= 2^-22 |x|
__device__ inline void split2(float x, half_t* h, half_t* l) {
    half_t hh = (half_t)x;
    float r = x - (float)hh;
    *h = hh;
    *l = (half_t)r;
}

// fp32 -> sortable-descending key32 (bigger score => smaller key)
__device__ inline unsigned score_key32(float s) {
    unsigned u = __builtin_bit_cast(unsigned, s);
    unsigned m = (u & 0x80000000u) ? ~u : (u | 0x80000000u);  // monotone asc
    return ~m;                                                 // desc
}

// ---------------------------------------------------------------------------
// prep (grid 1024x256): emb fp16-split + nesqh, zero f_hat output + hits,
// init pk keys to +inf, AND pool si=0 (pn=1: block = (b,c) pair, mean over
// 1024 px -> zhi/zlo) with per-block sumsq partials (deterministic, no
// atomics, no zero-init) for the loss.
__global__ __launch_bounds__(256) void prep_kernel(const float* __restrict__ f,
                                                   const float* __restrict__ emb,
                                                   half_t* __restrict__ ehi,
                                                   half_t* __restrict__ elo,
                                                   float* __restrict__ nesqh,
                                                   float* __restrict__ hits,
                                                   float* __restrict__ laccp,
                                                   half_t* __restrict__ zhi,
                                                   half_t* __restrict__ zlo,
                                                   u64_t* __restrict__ pk,
                                                   float* __restrict__ dout) {
    int gid = blockIdx.x * 256 + threadIdx.x;      // 262144 threads
    float4 z4 = {0.f, 0.f, 0.f, 0.f};
    *(float4*)(dout + (size_t)gid * 4) = z4;
    if (gid < VV) hits[gid] = 0.f;
    if (gid < NROWS_TOTAL) pk[gid] = ~0ull;        // +inf keys
    if (gid < VV) {
        int v = gid;
        const float* ep = emb + (size_t)v * CH;
        float s = 0.f;
        half_t h[CH], l[CH];
#pragma unroll
        for (int i = 0; i < CH; i++) {
            float e = ep[i];
            s = fmaf(e, e, s);
            split2(e, &h[i], &l[i]);
        }
        nesqh[v] = -0.5f * s;
#pragma unroll
        for (int q = 0; q < 4; q++) {
            half8 H, L;
#pragma unroll
            for (int k = 0; k < 8; k++) {
                H[k] = h[q * 8 + k];
                L[k] = l[q * 8 + k];
            }
            *(half8*)(ehi + (size_t)v * CH + q * 8) = H;
            *(half8*)(elo + (size_t)v * CH + q * 8) = L;
        }
    }

    // pool si=0: pair = blockIdx.x = b*32 + c; base = f + pair*1024
    const int pair = blockIdx.x;
    const float* base = f + (size_t)pair * 1024;
    float s = 0.f, s2 = 0.f;
    for (int p = threadIdx.x; p < 1024; p += 256) {
        float v = base[p];
        s += v;
        s2 = fmaf(v, v, s2);
    }
    __shared__ float sh[256], sh2[256];
    sh[threadIdx.x] = s;
    sh2[threadIdx.x] = s2;
    __syncthreads();
    for (int o = 128; o > 0; o >>= 1) {
        if (threadIdx.x < o) {
            sh[threadIdx.x]  += sh[threadIdx.x + o];
            sh2[threadIdx.x] += sh2[threadIdx.x + o];
        }
        __syncthreads();
    }
    if (threadIdx.x == 0) {
        split2(sh[0] * (1.0f / 1024.0f), &zhi[pair], &zlo[pair]);
        laccp[pair] = sh2[0];      // deterministic partial, summed in finalize
    }
}

// ---------------------------------------------------------------------------
// 3-MFMA fp16 score chain for one 16-row group vs one 16-code tile
// score = z.e - 0.5|e|^2 = ah.bh + ah.bl + al.bh  (al.bl <= 2^-22 dropped)
__device__ inline floatx4 score_chain(half8 ah, half8 al,
                                      half8 bh, half8 bl, floatx4 ehv) {
    floatx4 acc;
    acc = __builtin_amdgcn_mfma_f32_16x16x32_f16(ah, bh, ehv, 0, 0, 0);
    acc = __builtin_amdgcn_mfma_f32_16x16x32_f16(ah, bl, acc, 0, 0, 0);
    acc = __builtin_amdgcn_mfma_f32_16x16x32_f16(al, bh, acc, 0, 0, 0);
    return acc;
}

__device__ inline void sel4(const floatx4& acc, int v, float* best, int* bidx) {
#pragma unroll
    for (int r = 0; r < 4; r++) {
        // strict >: lane-local scan is increasing v -> keeps lowest v on tie
        if (acc[r] > best[r]) { best[r] = acc[r]; bidx[r] = v; }
    }
}

// argmin core (1-deep prefetch — the proven fastest of four structural
// variants: 2-deep pipe, VS ladders, pooled-stage all regressed or tied).
// Wave wv scans TPW v-tiles from t0+wv*TPW over RT 16-row tiles.
// Deferred-select interleave (RT>=2). Winner per row merged cross-block via
// packed-key atomicMin (max score, lowest idx on tie == jnp.argmin).
template <int RT, int TPW>
__device__ inline void argmin_body(const half8* a1, const half8* a2,
                                   const half_t* __restrict__ ehi,
                                   const half_t* __restrict__ elo,
                                   const float* __restrict__ nesqh,
                                   u64_t* __restrict__ pk, int row0, int t0) {
    const int tid  = threadIdx.x;
    const int wv   = tid >> 6;
    const int lane = tid & 63;
    const int col  = lane & 15;
    const int quad = lane >> 4;

    float best[RT][4];
    int   bidx[RT][4];
#pragma unroll
    for (int rt = 0; rt < RT; rt++)
#pragma unroll
        for (int r = 0; r < 4; r++) { best[rt][r] = -FLT_MAX; bidx[rt][r] = 0; }

    int t = t0 + wv * TPW;
    const int tend = t + TPW;

    // prefetch tile t
    size_t eoff = ((size_t)((t << 4) + col) << 5) + (quad << 3);
    half8 nb1 = *(const half8*)(ehi + eoff);
    half8 nb2 = *(const half8*)(elo + eoff);
    float neh = nesqh[(t << 4) + col];

    floatx4 acc[RT];
    int vprev = 0;
    if (RT > 1) acc[RT - 1] = floatx4{-FLT_MAX, -FLT_MAX, -FLT_MAX, -FLT_MAX};

    for (; t < tend; t++) {
        const half8 b1 = nb1, b2 = nb2;
        const floatx4 ehv = {neh, neh, neh, neh};
        const int vcur = (t << 4) + col;
        // prefetch t+1 (clamped) before consuming current
        const int tn = (t + 1 < tend) ? (t + 1) : t;
        const size_t eoff2 = ((size_t)((tn << 4) + col) << 5) + (quad << 3);
        nb1 = *(const half8*)(ehi + eoff2);
        nb2 = *(const half8*)(elo + eoff2);
        neh = nesqh[(tn << 4) + col];

        if (RT == 1) {
            acc[0] = score_chain(a1[0], a2[0], b1, b2, ehv);
            sel4(acc[0], vcur, best[0], bidx[0]);
        } else {
            acc[0] = score_chain(a1[0], a2[0], b1, b2, ehv);
            sel4(acc[RT - 1], vprev, best[RT - 1], bidx[RT - 1]);  // deferred
#pragma unroll
            for (int rt = 1; rt < RT; rt++) {
                acc[rt] = score_chain(a1[rt], a2[rt], b1, b2, ehv);
                sel4(acc[rt - 1], vcur, best[rt - 1], bidx[rt - 1]);
            }
            vprev = vcur;
        }
    }
    if (RT > 1) sel4(acc[RT - 1], vprev, best[RT - 1], bidx[RT - 1]);

    // reduce across the 16 cols (v within tile) of each quad group
#pragma unroll
    for (int m = 1; m < 16; m <<= 1) {
#pragma unroll
        for (int rt = 0; rt < RT; rt++)
#pragma unroll
            for (int r = 0; r < 4; r++) {
                float s2 = __shfl_xor(best[rt][r], m, 64);
                int   v2 = __shfl_xor(bidx[rt][r], m, 64);
                if (s2 > best[rt][r] ||
                    (s2 == best[rt][r] && v2 < bidx[rt][r])) {
                    best[rt][r] = s2; bidx[rt][r] = v2;
                }
            }
    }

    __shared__ float sbs[4 * RT * 16];
    __shared__ int   sbi[4 * RT * 16];
    if (col == 0) {
#pragma unroll
        for (int rt = 0; rt < RT; rt++)
#pragma unroll
            for (int r = 0; r < 4; r++) {
                int row = rt * 16 + (quad << 2) + r;
                sbs[wv * RT * 16 + row] = best[rt][r];
                sbi[wv * RT * 16 + row] = bidx[rt][r];
            }
    }
    __syncthreads();
    if (tid < RT * 16) {
        float s = sbs[tid];
        int   v = sbi[tid];
        for (int w = 1; w < 4; w++) {
            float s2 = sbs[w * RT * 16 + tid];
            int   v2 = sbi[w * RT * 16 + tid];
            if (s2 > s || (s2 == s && v2 < v)) { s = s2; v = v2; }
        }
        u64_t key = ((u64_t)score_key32(s) << 32) | (unsigned)v;
        atomicMin(pk + row0 + tid, key);
    }
}

// generic stage: z-splits from memory (si=0 only now). grid = (nRowBlocks, VS)
template <int RT, int VS>
__global__ __launch_bounds__(256) void argmin_stage(const half_t* __restrict__ zhi,
                                                    const half_t* __restrict__ zlo,
                                                    const half_t* __restrict__ ehi,
                                                    const half_t* __restrict__ elo,
                                                    const float* __restrict__ nesqh,
                                                    u64_t* __restrict__ pk) {
    const int lane = threadIdx.x & 63;
    const int col  = lane & 15;
    const int quad = lane >> 4;
    const int row0 = blockIdx.x * (16 * RT);

    half8 a1[RT], a2[RT];
#pragma unroll
    for (int rt = 0; rt < RT; rt++) {
        size_t off = ((size_t)(row0 + rt * 16 + col) << 5) + (quad << 3);
        a1[rt] = *(const half8*)(zhi + off);
        a2[rt] = *(const half8*)(zlo + off);
    }
    argmin_body<RT, 64 / VS>(a1, a2, ehi, elo, nesqh, pk,
                             row0, (int)blockIdx.y * (256 / VS));
}

// zp stage (si=1..4): pooled z comes as NSLOT fp32 partial sums written by the
// previous conv's epilogue. Sum partials in fixed slot order, scale by the
// exact power-of-two 1/ps'^2, split2 in-register. Row-coalesced loads
// (wave reads 16 contiguous 128B rows).
template <int RT, int VS, int NSLOT, int PN>
__global__ __launch_bounds__(256) void argmin_zp(const float* __restrict__ zp,
                                                 const half_t* __restrict__ ehi,
                                                 const half_t* __restrict__ elo,
                                                 const float* __restrict__ nesqh,
                                                 u64_t* __restrict__ pk) {
    const int lane = threadIdx.x & 63;
    const int col  = lane & 15;
    const int quad = lane >> 4;
    const int row0 = blockIdx.x * (16 * RT);
    constexpr int ZSTR = BS * PN * PN * CH;
    constexpr int PSP  = 32 / PN;
    const float scale = 1.0f / (float)(PSP * PSP);

    half8 a1[RT], a2[RT];
#pragma unroll
    for (int rt = 0; rt < RT; rt++) {
        const float* p = zp + (size_t)(row0 + rt * 16 + col) * CH + (quad << 3);
        float4 v0 = *(const float4*)p;
        float4 v1 = *(const float4*)(p + 4);
#pragma unroll
        for (int sl = 1; sl < NSLOT; sl++) {
            float4 u0 = *(const float4*)(p + (size_t)sl * ZSTR);
            float4 u1 = *(const float4*)(p + (size_t)sl * ZSTR + 4);
            v0.x += u0.x; v0.y += u0.y; v0.z += u0.z; v0.w += u0.w;
            v1.x += u1.x; v1.y += u1.y; v1.z += u1.z; v1.w += u1.w;
        }
        float s[8] = {v0.x, v0.y, v0.z, v0.w, v1.x, v1.y, v1.z, v1.w};
#pragma unroll
        for (int k = 0; k < 8; k++) {
            half_t h, l;
            split2(s[k] * scale, &h, &l);
            a1[rt][k] = h; a2[rt][k] = l;
        }
    }
    argmin_body<RT, 64 / VS>(a1, a2, ehi, elo, nesqh, pk,
                             row0, (int)blockIdx.y * (256 / VS));
}

// si=5 fused: pool is identity (pn=32) -> split2 straight from frest.
// grid = (512, 2): RT=4, VS=2, each wave scans 32 tiles. (r10/r14-proven;
// VS=4, 2-deep pipe, and external-pool variants all regressed or tied.)
__global__ __launch_bounds__(256) void argmin5_fused(const float* __restrict__ frest,
                                                     const half_t* __restrict__ ehi,
                                                     const half_t* __restrict__ elo,
                                                     const float* __restrict__ nesqh,
                                                     u64_t* __restrict__ pk) {
    const int lane = threadIdx.x & 63;
    const int col  = lane & 15;
    const int quad = lane >> 4;
    const int row0 = blockIdx.x * 64;   // RT=4

    half8 a1[4], a2[4];
#pragma unroll
    for (int rt = 0; rt < 4; rt++) {
        int n = row0 + rt * 16 + col;               // row = (b*32+i)*32+j
        int b = n >> 10, i = (n >> 5) & 31, j = n & 31;
        const float* p = frest + ((((size_t)(b * CH + quad * 8)) * HH + i) * HH + j);
#pragma unroll
        for (int k = 0; k < 8; k++) {
            half_t h, l;
            split2(p[(size_t)k * (HH * HH)], &h, &l);   // c stride = 1024
            a1[rt][k] = h; a2[rt][k] = l;
        }
    }
    argmin_body<4, 32>(a1, a2, ehi, elo, nesqh, pk,
                       row0, (int)blockIdx.y * 128);
}

// ---------------------------------------------------------------------------
// bicubic weights, a=-0.75, half-pixel, edge clamp (matches ref _bicubic_mat)
__device__ inline void cubic_w(float xs, int pn, int* ix, float* w) {
    const float a = -0.75f;
    float xf = floorf(xs);
    int x0 = (int)xf;
    float t = xs - xf;
#pragma unroll
    for (int j = -1; j <= 2; j++) {
        float d = fabsf(t - (float)j);
        float ww;
        if (d < 1.0f)      ww = ((a + 2.0f) * d - (a + 3.0f)) * d * d + 1.0f;
        else if (d < 2.0f) ww = ((a * d - 5.0f * a) * d + 8.0f * a) * d - 4.0f * a;
        else               ww = 0.0f;
        int xi = x0 + j;
        xi = xi < 0 ? 0 : (xi > pn - 1 ? pn - 1 : xi);
        ix[j + 1] = xi;
        w[j + 1]  = ww;
    }
}

// ---------------------------------------------------------------------------
// FUSED upsample + Phi + residual: dst = src - (0.5*h + 0.5*(conv3x3(h)+bias))
// h = bicubic_upsample(emb[winner_idx]) computed during LDS staging with
// bit-identical fma order to the old upsample_gather_kernel. The needed emb
// rows (iy-band <=8 x PN cols x 16 ch) are first gathered into LDS with
// coalesced loads, and the 16 bicubic taps read LDS (r3-proven: conv fell
// 200us -> <42us vs r2's scattered-gather variant).
// grid: b(32) x yt(8) x co-quarter(4) = 1024 blocks; block 256 = tx(32) x ty(8).
// PN_NEXT != 0 pools dst for the next scale into fp32 partial-sum slots.
template <int PN, int PN_NEXT>
__global__ __launch_bounds__(256) void conv_fused_kernel(const u64_t* __restrict__ pk,
                                                         const float* __restrict__ emb,
                                                         const float* __restrict__ w,
                                                         const float* __restrict__ bias,
                                                         const float* __restrict__ src,
                                                         float* __restrict__ dst,
                                                         float* __restrict__ zp) {
    constexpr int IYB = (PN <= 4) ? PN : 8;   // cached iy-band height (tap span <=7)
    const int coq = blockIdx.x & 3;
    const int yt  = (blockIdx.x >> 2) & 7;
    const int b   = blockIdx.x >> 5;
    const int tx  = threadIdx.x & 31;
    const int ty  = threadIdx.x >> 5;     // 0..7
    const int y0  = yt * 4;

    __shared__ float wl[8 * 32 * 12];     // 12 KB
    __shared__ float til[16 * 6 * 34];    // 13.1 KB
    __shared__ int   idxg[PN * PN];       // winner indices for this b
    __shared__ int   riy[6][4];           // row bicubic windows (gy = y0-1..y0+4)
    __shared__ float rwy[6][4];
    __shared__ int   cix[34][4];          // col bicubic windows (gx = -1..32)
    __shared__ float cwx[34][4];
    // emb-row cache: [ch 16][iy band][ix + pad] — ch-major so tap reads
    // (lanes differ in ix) are bank-conflict-free; +1 pad de-conflicts writes.
    __shared__ float cache[16][IYB][PN + 1];

    {
        const float* wsrc = w + (size_t)coq * 8 * CH * 9;
        for (int i = threadIdx.x; i < 8 * 32 * 12; i += 256) {
            int k = i % 12;
            wl[i] = (k < 9) ? wsrc[(i / 12) * 9 + k] : 0.f;
        }
    }
    // winner index grid for this batch image
    for (int i = threadIdx.x; i < PN * PN; i += 256)
        idxg[i] = (int)(unsigned)(pk[b * PN * PN + i] & 0xFFFFFFFFull);
    // bicubic windows (rows by wave 0, cols by wave 1 -> parallel)
    const float scale = (float)PN / (float)HH;
    if (threadIdx.x < 6) {
        int r = threadIdx.x;
        int iy[4]; float wy[4];
        cubic_w(((float)(y0 - 1 + r) + 0.5f) * scale - 0.5f, PN, iy, wy);
#pragma unroll
        for (int a = 0; a < 4; a++) { riy[r][a] = iy[a]; rwy[r][a] = wy[a]; }
    }
    if (threadIdx.x >= 64 && threadIdx.x < 98) {
        int cl = threadIdx.x - 64;        // col 0..33, gx = cl-1
        int ix[4]; float wx[4];
        cubic_w(((float)(cl - 1) + 0.5f) * scale - 0.5f, PN, ix, wx);
#pragma unroll
        for (int a = 0; a < 4; a++) { cix[cl][a] = ix[a]; cwx[cl][a] = wx[a]; }
    }

    // iy-band start: covers all clamped taps of gy in [y0-1, y0+4].
    // Computed redundantly per-thread (deterministic). For PN<=4 band = grid.
    int iy_lo = 0;
    if (PN > 4) {
        int lo = (int)floorf(((float)(y0 - 1) + 0.5f) * scale - 0.5f) - 1;
        if (lo < 0) lo = 0;
        if (lo > PN - IYB) lo = PN - IYB;
        iy_lo = lo;
    }

    const int co = coq * 8 + ty;
    float acc[4];
#pragma unroll
    for (int ry = 0; ry < 4; ry++) acc[ry] = bias[co];
    float hcv[4];

    for (int cc = 0; cc < 2; cc++) {
        __syncthreads();                  // idxg/windows ready (iter 0); til free
        // gather emb rows for this cc half into cache (coalesced: 16
        // consecutive ch floats per cell)
        for (int i = threadIdx.x; i < IYB * PN * 16; i += 256) {
            int cil  = i & 15;
            int cell = i >> 4;
            int ix   = cell % PN;
            int iyb  = cell / PN;
            int idx  = idxg[(iy_lo + iyb) * PN + ix];
            cache[cil][iyb][ix] = emb[(size_t)idx * CH + cc * 16 + cil];
        }
        __syncthreads();
        // stage input: ci = cc*16 + 0..15, rows y0-1..y0+4, cols -1..32.
        // Each element is the bicubic upsample value (zero for pad), taps
        // read from the LDS cache (bit-identical values & fma order).
        for (int i = threadIdx.x; i < 16 * 6 * 34; i += 256) {
            int col = i % 34;
            int row = (i / 34) % 6;
            int cil = i / 204;
            int gy = y0 - 1 + row;
            int gx = col - 1;
            float vv = 0.f;
            if ((unsigned)gy < 32u && (unsigned)gx < 32u) {
                float s = 0.f;
#pragma unroll
                for (int a = 0; a < 4; a++) {
                    const int iyb = riy[row][a] - iy_lo;
                    float rsum = 0.f;
#pragma unroll
                    for (int b2 = 0; b2 < 4; b2++) {
                        rsum = fmaf(cache[cil][iyb][cix[col][b2]],
                                    cwx[col][b2], rsum);
                    }
                    s = fmaf(rsum, rwy[row][a], s);
                }
                vv = s;
            }
            til[i] = vv;
        }
        __syncthreads();

        // capture h at this thread's own output positions (channel co) from LDS
        if (cc == (co >> 4)) {
#pragma unroll
            for (int ry = 0; ry < 4; ry++)
                hcv[ry] = til[(co & 15) * 204 + (ry + 1) * 34 + (tx + 1)];
        }

        for (int cil = 0; cil < 16; cil++) {
            float in[6][3];
            const float* tp = &til[cil * 204];
#pragma unroll
            for (int rr2 = 0; rr2 < 6; rr2++)
#pragma unroll
                for (int dx = 0; dx < 3; dx++)
                    in[rr2][dx] = tp[rr2 * 34 + tx + dx];
            const float* wp = &wl[(ty * 32 + cc * 16 + cil) * 12];
            float4 wa = *(const float4*)wp;
            float4 wb = *(const float4*)(wp + 4);
            float  w8 = wp[8];
#pragma unroll
            for (int ry = 0; ry < 4; ry++) {
                float s = acc[ry];
                s = fmaf(in[ry + 0][0], wa.x, s);
                s = fmaf(in[ry + 0][1], wa.y, s);
                s = fmaf(in[ry + 0][2], wa.z, s);
                s = fmaf(in[ry + 1][0], wa.w, s);
                s = fmaf(in[ry + 1][1], wb.x, s);
                s = fmaf(in[ry + 1][2], wb.y, s);
                s = fmaf(in[ry + 2][0], wb.z, s);
                s = fmaf(in[ry + 2][1], wb.w, s);
                s = fmaf(in[ry + 2][2], w8,   s);
                acc[ry] = s;
            }
        }
    }

    float pv[4];
#pragma unroll
    for (int ry = 0; ry < 4; ry++) {
        size_t off = (((size_t)(b * CH + co)) * HH + (y0 + ry)) * HH + tx;
        float dv = src[off] - (0.5f * hcv[ry] + 0.5f * acc[ry]);
        dst[off] = dv;
        pv[ry] = dv;
    }

    if constexpr (PN_NEXT != 0) {
        constexpr int PSP  = 32 / PN_NEXT;               // 16/8/4/2
        constexpr int NWY  = (PSP == 2) ? 2 : 1;         // windows along y in this block
        constexpr int ZSTR = BS * PN_NEXT * PN_NEXT * CH;
        float wsum[NWY];
#pragma unroll
        for (int k = 0; k < NWY; k++) wsum[k] = 0.f;
#pragma unroll
        for (int ry = 0; ry < 4; ry++) wsum[(NWY == 2) ? (ry >> 1) : 0] += pv[ry];
        // reduce across tx groups of PSP lanes (tx = lane&31, tx is lane-minor)
#pragma unroll
        for (int m = 1; m < PSP; m <<= 1) {
#pragma unroll
            for (int k = 0; k < NWY; k++) wsum[k] += __shfl_xor(wsum[k], m, 64);
        }
        if ((tx & (PSP - 1)) == 0) {
            const int wx   = tx / PSP;
            const int slot = (PSP == 16) ? (yt & 3) : (PSP == 8) ? (yt & 1) : 0;
#pragma unroll
            for (int k = 0; k < NWY; k++) {
                const int wy = (PSP == 2) ? (yt * 2 + k) : (y0 / PSP);
                zp[(size_t)slot * ZSTR +
                   ((size_t)((b * PN_NEXT + wy) * PN_NEXT + wx)) * CH + co] = wsum[k];
            }
        }
    }
}

// ---------------------------------------------------------------------------
// hits bincount over all scales' packed winners (multi-block, parallel —
// r3 lesson: single-block LDS-hist finalize was a 60us serial tail; 171
// parallel blocks with global atomics never crack the top-5)
__global__ __launch_bounds__(256) void bincount_kernel(const u64_t* __restrict__ pk,
                                                       float* __restrict__ hits, int n) {
    int i = blockIdx.x * 256 + threadIdx.x;
    if (i < n) {
        int idx = (int)(unsigned)(pk[i] & 0xFFFFFFFFull);
        atomicAdd(&hits[idx], 1.0f);
    }
}

// ---------------------------------------------------------------------------
// perplexity + loss finalize (single block; reads only 4096-entry hist +
// 1024 lacc partials = 20 KB)
__global__ __launch_bounds__(256) void finalize_kernel(const float* __restrict__ hits,
                                                       const float* __restrict__ laccp,
                                                       float* __restrict__ outs) {
    __shared__ float sh[256];
    int t = threadIdx.x;
    // total = NROWS_TOTAL exactly (each row contributes one hit)
    const float tot = (float)NROWS_TOTAL;
    float ent = 0.f;
    for (int v = t; v < VV; v += 256) {
        float p = hits[v] / tot;
        ent += p * logf(p + 1e-10f);
    }
    sh[t] = ent;
    __syncthreads();
    for (int o = 128; o > 0; o >>= 1) {
        if (t < o) sh[t] += sh[t + o];
        __syncthreads();
    }
    float entT = sh[0];            // valid for all after the synced tree
    __syncthreads();
    float ls = 0.f;
    for (int i = t; i < 1024; i += 256) ls += laccp[i];
    sh[t] = ls;
    __syncthreads();
    for (int o = 128; o > 0; o >>= 1) {
        if (t < o) sh[t] += sh[t + o];
        __syncthreads();
    }
    if (t == 0) {
        // loss = SN*(1+BETA)*mean(f^2) = 7.5 * sumsq / 1048576  (f_hat stays 0)
        outs[0] = 7.5f * sh[0] * (1.0f / (float)FELEMS);
        outs[1] = expf(-entT);
    }
}

// ---------------------------------------------------------------------------
extern "C" void kernel_launch(void* const* d_in, const int* in_sizes, int n_in,
                              void* d_out, int out_size, void* d_ws, size_t ws_size,
                              hipStream_t stream) {
    const float* f   = (const float*)d_in[0];   // (32,32,32,32)
    const float* emb = (const float*)d_in[1];   // (4096,32)
    const float* phw = (const float*)d_in[2];   // (4,32,32,3,3)
    const float* phb = (const float*)d_in[3];   // (4,32)
    float* out = (float*)d_out;                 // f_hat (1048576) + loss + perplexity

    float* ws      = (float*)d_ws;
    float* hits    = ws;                              // [0, 4096)
    float* laccp   = ws + 4096;                       // [4096, 5120) partials
    u64_t* pkbase  = (u64_t*)(ws + 8448);             // 43680 u64 -> [8448, 95808)
    float* frest   = ws + 95808;                      // [95808, 1144384)
    half_t* zhi    = (half_t*)(ws + 1144384);         // si=0 z-split (1024 used)
    half_t* zlo    = (half_t*)(ws + 1275456);
    float* nesqh   = ws + 1537600;                    // [1537600, 1541696)
    half_t* ehi    = (half_t*)(ws + 2590272);         // 131072 halves = 65536 f
    half_t* elo    = (half_t*)(ws + 2655808);         // ends 2721344
    float* zp      = ws + 2721344;                    // 262144 f -> ends 2983488 (11.9 MB)

    // prep: emb split + nesqh + zero f_hat/hits + pk=+inf + pool si=0 + lacc
    prep_kernel<<<1024, 256, 0, stream>>>(f, emb, ehi, elo, nesqh, hits, laccp,
                                          zhi, zlo, pkbase, out);

    const int pkoff[6] = {0, 32, 160, 672, 2720, 10912};
    const size_t WSTR = (size_t)CH * CH * 9;          // 9216 per phi

    // si=0 (pn=1, sel=0): argmin from prep's z-split; conv pools for pn=2 (4 slots)
    argmin_stage<1, 16><<<dim3(2, 16), 256, 0, stream>>>(zhi, zlo, ehi, elo, nesqh,
                                                         pkbase + pkoff[0]);
    conv_fused_kernel<1, 2><<<1024, 256, 0, stream>>>(pkbase + pkoff[0], emb,
                                                      phw + 0 * WSTR, phb + 0 * CH,
                                                      f, frest, zp);

    // si=1 (pn=2, sel=0): z from 4 fp32 partials; conv pools for pn=4 (2 slots)
    argmin_zp<1, 16, 4, 2><<<dim3(8, 16), 256, 0, stream>>>(zp, ehi, elo, nesqh,
                                                            pkbase + pkoff[1]);
    conv_fused_kernel<2, 4><<<1024, 256, 0, stream>>>(pkbase + pkoff[1], emb,
                                                      phw + 0 * WSTR, phb + 0 * CH,
                                                      frest, frest, zp);

    // si=2 (pn=4, sel=1): z from 2 partials; conv pools for pn=8 (1 slot)
    argmin_zp<1, 16, 2, 4><<<dim3(32, 16), 256, 0, stream>>>(zp, ehi, elo, nesqh,
                                                             pkbase + pkoff[2]);
    conv_fused_kernel<4, 8><<<1024, 256, 0, stream>>>(pkbase + pkoff[2], emb,
                                                      phw + 1 * WSTR, phb + 1 * CH,
                                                      frest, frest, zp);

    // si=3 (pn=8, sel=2): z from 1 partial; conv pools for pn=16 (1 slot)
    argmin_zp<1, 8, 1, 8><<<dim3(128, 8), 256, 0, stream>>>(zp, ehi, elo, nesqh,
                                                            pkbase + pkoff[3]);
    conv_fused_kernel<8, 16><<<1024, 256, 0, stream>>>(pkbase + pkoff[3], emb,
                                                       phw + 2 * WSTR, phb + 2 * CH,
                                                       frest, frest, zp);

    // si=4 (pn=16, sel=3): z from 1 partial; conv has no pooling (si=5 reads frest)
    argmin_zp<2, 4, 1, 16><<<dim3(256, 4), 256, 0, stream>>>(zp, ehi, elo, nesqh,
                                                             pkbase + pkoff[4]);
    conv_fused_kernel<16, 0><<<1024, 256, 0, stream>>>(pkbase + pkoff[4], emb,
                                                       phw + 3 * WSTR, phb + 3 * CH,
                                                       frest, frest, nullptr);

    // si=5 (pn=32, sel=3): fused identity-pool argmin straight from frest
    argmin5_fused<<<dim3(512, 2), 256, 0, stream>>>(frest, ehi, elo, nesqh,
                                                    pkbase + pkoff[5]);

    bincount_kernel<<<(NROWS_TOTAL + 255) / 256, 256, 0, stream>>>(pkbase, hits, NROWS_TOTAL);
    finalize_kernel<<<1, 256, 0, stream>>>(hits, laccp, out + (out_size - 2));
}

// Round 5
// 304.906 us; speedup vs baseline: 2.5829x; 1.1319x over previous
//
#include <hip/hip_runtime.h>
#include <math.h>
#include <float.h>

// Problem constants (B=32, C=32, H=W=32, V=4096)
#define BS    32
#define CH    32
#define HH    32
#define VV    4096
#define FELEMS (BS*CH*HH*HH)   // 1048576
#define NROWS_TOTAL 43680      // sum over scales of B*pn*pn

typedef unsigned short ushort_t;
typedef unsigned long long u64_t;
typedef _Float16 half_t;
typedef __attribute__((ext_vector_type(8))) _Float16 half8;
typedef __attribute__((ext_vector_type(4))) float floatx4;

// 2-way fp16 split: x ~= h + l, residual <= 2^-22 |x|
__device__ inline void split2(float x, half_t* h, half_t* l) {
    half_t hh = (half_t)x;
    float r = x - (float)hh;
    *h = hh;
    *l = (half_t)r;
}

// fp32 -> sortable-descending key32 (bigger score => smaller key)
__device__ inline unsigned score_key32(float s) {
    unsigned u = __builtin_bit_cast(unsigned, s);
    unsigned m = (u & 0x80000000u) ? ~u : (u | 0x80000000u);  // monotone asc
    return ~m;                                                 // desc
}

// ---------------------------------------------------------------------------
// prep (grid 1024x256): emb fp16-split + nesqh, zero f_hat output + hits,
// init pk keys to +inf, AND pool si=0 (pn=1: block = (b,c) pair, mean over
// 1024 px -> zhi/zlo) with per-block sumsq partials (deterministic, no
// atomics, no zero-init) for the loss.
__global__ __launch_bounds__(256) void prep_kernel(const float* __restrict__ f,
                                                   const float* __restrict__ emb,
                                                   half_t* __restrict__ ehi,
                                                   half_t* __restrict__ elo,
                                                   float* __restrict__ nesqh,
                                                   float* __restrict__ hits,
                                                   float* __restrict__ laccp,
                                                   half_t* __restrict__ zhi,
                                                   half_t* __restrict__ zlo,
                                                   u64_t* __restrict__ pk,
                                                   float* __restrict__ dout) {
    int gid = blockIdx.x * 256 + threadIdx.x;      // 262144 threads
    float4 z4 = {0.f, 0.f, 0.f, 0.f};
    *(float4*)(dout + (size_t)gid * 4) = z4;
    if (gid < VV) hits[gid] = 0.f;
    if (gid < NROWS_TOTAL) pk[gid] = ~0ull;        // +inf keys
    if (gid < VV) {
        int v = gid;
        const float* ep = emb + (size_t)v * CH;
        float s = 0.f;
        half_t h[CH], l[CH];
#pragma unroll
        for (int i = 0; i < CH; i++) {
            float e = ep[i];
            s = fmaf(e, e, s);
            split2(e, &h[i], &l[i]);
        }
        nesqh[v] = -0.5f * s;
#pragma unroll
        for (int q = 0; q < 4; q++) {
            half8 H, L;
#pragma unroll
            for (int k = 0; k < 8; k++) {
                H[k] = h[q * 8 + k];
                L[k] = l[q * 8 + k];
            }
            *(half8*)(ehi + (size_t)v * CH + q * 8) = H;
            *(half8*)(elo + (size_t)v * CH + q * 8) = L;
        }
    }

    // pool si=0: pair = blockIdx.x = b*32 + c; base = f + pair*1024
    const int pair = blockIdx.x;
    const float* base = f + (size_t)pair * 1024;
    float s = 0.f, s2 = 0.f;
    for (int p = threadIdx.x; p < 1024; p += 256) {
        float v = base[p];
        s += v;
        s2 = fmaf(v, v, s2);
    }
    __shared__ float sh[256], sh2[256];
    sh[threadIdx.x] = s;
    sh2[threadIdx.x] = s2;
    __syncthreads();
    for (int o = 128; o > 0; o >>= 1) {
        if (threadIdx.x < o) {
            sh[threadIdx.x]  += sh[threadIdx.x + o];
            sh2[threadIdx.x] += sh2[threadIdx.x + o];
        }
        __syncthreads();
    }
    if (threadIdx.x == 0) {
        split2(sh[0] * (1.0f / 1024.0f), &zhi[pair], &zlo[pair]);
        laccp[pair] = sh2[0];      // deterministic partial, summed in finalize
    }
}

// ---------------------------------------------------------------------------
// 3-MFMA fp16 score chain for one 16-row group vs one 16-code tile
// score = z.e - 0.5|e|^2 = ah.bh + ah.bl + al.bh  (al.bl <= 2^-22 dropped)
__device__ inline floatx4 score_chain(half8 ah, half8 al,
                                      half8 bh, half8 bl, floatx4 ehv) {
    floatx4 acc;
    acc = __builtin_amdgcn_mfma_f32_16x16x32_f16(ah, bh, ehv, 0, 0, 0);
    acc = __builtin_amdgcn_mfma_f32_16x16x32_f16(ah, bl, acc, 0, 0, 0);
    acc = __builtin_amdgcn_mfma_f32_16x16x32_f16(al, bh, acc, 0, 0, 0);
    return acc;
}

__device__ inline void sel4(const floatx4& acc, int v, float* best, int* bidx) {
#pragma unroll
    for (int r = 0; r < 4; r++) {
        // strict >: lane-local scan is increasing v -> keeps lowest v on tie
        if (acc[r] > best[r]) { best[r] = acc[r]; bidx[r] = v; }
    }
}

// argmin core (1-deep prefetch — the proven fastest of four structural
// variants: 2-deep pipe, VS ladders, pooled-stage all regressed or tied).
// Wave wv scans TPW v-tiles from t0+wv*TPW over RT 16-row tiles.
// Deferred-select interleave (RT>=2). Winner per row merged cross-block via
// packed-key atomicMin (max score, lowest idx on tie == jnp.argmin).
template <int RT, int TPW>
__device__ inline void argmin_body(const half8* a1, const half8* a2,
                                   const half_t* __restrict__ ehi,
                                   const half_t* __restrict__ elo,
                                   const float* __restrict__ nesqh,
                                   u64_t* __restrict__ pk, int row0, int t0) {
    const int tid  = threadIdx.x;
    const int wv   = tid >> 6;
    const int lane = tid & 63;
    const int col  = lane & 15;
    const int quad = lane >> 4;

    float best[RT][4];
    int   bidx[RT][4];
#pragma unroll
    for (int rt = 0; rt < RT; rt++)
#pragma unroll
        for (int r = 0; r < 4; r++) { best[rt][r] = -FLT_MAX; bidx[rt][r] = 0; }

    int t = t0 + wv * TPW;
    const int tend = t + TPW;

    // prefetch tile t
    size_t eoff = ((size_t)((t << 4) + col) << 5) + (quad << 3);
    half8 nb1 = *(const half8*)(ehi + eoff);
    half8 nb2 = *(const half8*)(elo + eoff);
    float neh = nesqh[(t << 4) + col];

    floatx4 acc[RT];
    int vprev = 0;
    if (RT > 1) acc[RT - 1] = floatx4{-FLT_MAX, -FLT_MAX, -FLT_MAX, -FLT_MAX};

    for (; t < tend; t++) {
        const half8 b1 = nb1, b2 = nb2;
        const floatx4 ehv = {neh, neh, neh, neh};
        const int vcur = (t << 4) + col;
        // prefetch t+1 (clamped) before consuming current
        const int tn = (t + 1 < tend) ? (t + 1) : t;
        const size_t eoff2 = ((size_t)((tn << 4) + col) << 5) + (quad << 3);
        nb1 = *(const half8*)(ehi + eoff2);
        nb2 = *(const half8*)(elo + eoff2);
        neh = nesqh[(tn << 4) + col];

        if (RT == 1) {
            acc[0] = score_chain(a1[0], a2[0], b1, b2, ehv);
            sel4(acc[0], vcur, best[0], bidx[0]);
        } else {
            acc[0] = score_chain(a1[0], a2[0], b1, b2, ehv);
            sel4(acc[RT - 1], vprev, best[RT - 1], bidx[RT - 1]);  // deferred
#pragma unroll
            for (int rt = 1; rt < RT; rt++) {
                acc[rt] = score_chain(a1[rt], a2[rt], b1, b2, ehv);
                sel4(acc[rt - 1], vcur, best[rt - 1], bidx[rt - 1]);
            }
            vprev = vcur;
        }
    }
    if (RT > 1) sel4(acc[RT - 1], vprev, best[RT - 1], bidx[RT - 1]);

    // reduce across the 16 cols (v within tile) of each quad group
#pragma unroll
    for (int m = 1; m < 16; m <<= 1) {
#pragma unroll
        for (int rt = 0; rt < RT; rt++)
#pragma unroll
            for (int r = 0; r < 4; r++) {
                float s2 = __shfl_xor(best[rt][r], m, 64);
                int   v2 = __shfl_xor(bidx[rt][r], m, 64);
                if (s2 > best[rt][r] ||
                    (s2 == best[rt][r] && v2 < bidx[rt][r])) {
                    best[rt][r] = s2; bidx[rt][r] = v2;
                }
            }
    }

    __shared__ float sbs[4 * RT * 16];
    __shared__ int   sbi[4 * RT * 16];
    if (col == 0) {
#pragma unroll
        for (int rt = 0; rt < RT; rt++)
#pragma unroll
            for (int r = 0; r < 4; r++) {
                int row = rt * 16 + (quad << 2) + r;
                sbs[wv * RT * 16 + row] = best[rt][r];
                sbi[wv * RT * 16 + row] = bidx[rt][r];
            }
    }
    __syncthreads();
    if (tid < RT * 16) {
        float s = sbs[tid];
        int   v = sbi[tid];
        for (int w = 1; w < 4; w++) {
            float s2 = sbs[w * RT * 16 + tid];
            int   v2 = sbi[w * RT * 16 + tid];
            if (s2 > s || (s2 == s && v2 < v)) { s = s2; v = v2; }
        }
        u64_t key = ((u64_t)score_key32(s) << 32) | (unsigned)v;
        atomicMin(pk + row0 + tid, key);
    }
}

// generic stage: z-splits from memory (si=0 only now). grid = (nRowBlocks, VS)
template <int RT, int VS>
__global__ __launch_bounds__(256) void argmin_stage(const half_t* __restrict__ zhi,
                                                    const half_t* __restrict__ zlo,
                                                    const half_t* __restrict__ ehi,
                                                    const half_t* __restrict__ elo,
                                                    const float* __restrict__ nesqh,
                                                    u64_t* __restrict__ pk) {
    const int lane = threadIdx.x & 63;
    const int col  = lane & 15;
    const int quad = lane >> 4;
    const int row0 = blockIdx.x * (16 * RT);

    half8 a1[RT], a2[RT];
#pragma unroll
    for (int rt = 0; rt < RT; rt++) {
        size_t off = ((size_t)(row0 + rt * 16 + col) << 5) + (quad << 3);
        a1[rt] = *(const half8*)(zhi + off);
        a2[rt] = *(const half8*)(zlo + off);
    }
    argmin_body<RT, 64 / VS>(a1, a2, ehi, elo, nesqh, pk,
                             row0, (int)blockIdx.y * (256 / VS));
}

// zp stage (si=1..4): pooled z comes as NSLOT fp32 partial sums written by the
// previous conv's epilogue. Sum partials in fixed slot order, scale by the
// exact power-of-two 1/ps'^2, split2 in-register. Row-coalesced loads
// (wave reads 16 contiguous 128B rows).
template <int RT, int VS, int NSLOT, int PN>
__global__ __launch_bounds__(256) void argmin_zp(const float* __restrict__ zp,
                                                 const half_t* __restrict__ ehi,
                                                 const half_t* __restrict__ elo,
                                                 const float* __restrict__ nesqh,
                                                 u64_t* __restrict__ pk) {
    const int lane = threadIdx.x & 63;
    const int col  = lane & 15;
    const int quad = lane >> 4;
    const int row0 = blockIdx.x * (16 * RT);
    constexpr int ZSTR = BS * PN * PN * CH;
    constexpr int PSP  = 32 / PN;
    const float scale = 1.0f / (float)(PSP * PSP);

    half8 a1[RT], a2[RT];
#pragma unroll
    for (int rt = 0; rt < RT; rt++) {
        const float* p = zp + (size_t)(row0 + rt * 16 + col) * CH + (quad << 3);
        float4 v0 = *(const float4*)p;
        float4 v1 = *(const float4*)(p + 4);
#pragma unroll
        for (int sl = 1; sl < NSLOT; sl++) {
            float4 u0 = *(const float4*)(p + (size_t)sl * ZSTR);
            float4 u1 = *(const float4*)(p + (size_t)sl * ZSTR + 4);
            v0.x += u0.x; v0.y += u0.y; v0.z += u0.z; v0.w += u0.w;
            v1.x += u1.x; v1.y += u1.y; v1.z += u1.z; v1.w += u1.w;
        }
        float s[8] = {v0.x, v0.y, v0.z, v0.w, v1.x, v1.y, v1.z, v1.w};
#pragma unroll
        for (int k = 0; k < 8; k++) {
            half_t h, l;
            split2(s[k] * scale, &h, &l);
            a1[rt][k] = h; a2[rt][k] = l;
        }
    }
    argmin_body<RT, 64 / VS>(a1, a2, ehi, elo, nesqh, pk,
                             row0, (int)blockIdx.y * (256 / VS));
}

// si=5 fused: pool is identity (pn=32) -> split2 straight from frest.
// grid = (512, 2): RT=4, VS=2, each wave scans 32 tiles. (r10/r14-proven;
// VS=4, 2-deep pipe, and external-pool variants all regressed or tied.)
__global__ __launch_bounds__(256) void argmin5_fused(const float* __restrict__ frest,
                                                     const half_t* __restrict__ ehi,
                                                     const half_t* __restrict__ elo,
                                                     const float* __restrict__ nesqh,
                                                     u64_t* __restrict__ pk) {
    const int lane = threadIdx.x & 63;
    const int col  = lane & 15;
    const int quad = lane >> 4;
    const int row0 = blockIdx.x * 64;   // RT=4

    half8 a1[4], a2[4];
#pragma unroll
    for (int rt = 0; rt < 4; rt++) {
        int n = row0 + rt * 16 + col;               // row = (b*32+i)*32+j
        int b = n >> 10, i = (n >> 5) & 31, j = n & 31;
        const float* p = frest + ((((size_t)(b * CH + quad * 8)) * HH + i) * HH + j);
#pragma unroll
        for (int k = 0; k < 8; k++) {
            half_t h, l;
            split2(p[(size_t)k * (HH * HH)], &h, &l);   // c stride = 1024
            a1[rt][k] = h; a2[rt][k] = l;
        }
    }
    argmin_body<4, 32>(a1, a2, ehi, elo, nesqh, pk,
                       row0, (int)blockIdx.y * 128);
}

// ---------------------------------------------------------------------------
// bicubic weights, a=-0.75, half-pixel, edge clamp (matches ref _bicubic_mat)
__device__ inline void cubic_w(float xs, int pn, int* ix, float* w) {
    const float a = -0.75f;
    float xf = floorf(xs);
    int x0 = (int)xf;
    float t = xs - xf;
#pragma unroll
    for (int j = -1; j <= 2; j++) {
        float d = fabsf(t - (float)j);
        float ww;
        if (d < 1.0f)      ww = ((a + 2.0f) * d - (a + 3.0f)) * d * d + 1.0f;
        else if (d < 2.0f) ww = ((a * d - 5.0f * a) * d + 8.0f * a) * d - 4.0f * a;
        else               ww = 0.0f;
        int xi = x0 + j;
        xi = xi < 0 ? 0 : (xi > pn - 1 ? pn - 1 : xi);
        ix[j + 1] = xi;
        w[j + 1]  = ww;
    }
}

// ---------------------------------------------------------------------------
// FUSED upsample + Phi + residual: dst = src - (0.5*h + 0.5*(conv3x3(h)+bias))
// h = bicubic_upsample(emb[winner_idx]) computed during LDS staging with
// bit-identical fma order to the original upsample kernel; taps read an LDS
// emb-cache (r3-proven). r5 CHANGE: ONE 1024-thread block per (b,yt) computes
// all 32 co (was 4 coq blocks x 256) — til/cache/idxg/window staging and the
// scattered emb gathers now happen once per tile instead of 4x. Weights
// packed [co][ci][9] (36.9 KB); total LDS 60.9 KB; 16 waves/block.
// PN_NEXT != 0 pools dst for the next scale into fp32 partial-sum slots.
template <int PN, int PN_NEXT>
__global__ __launch_bounds__(1024) void conv_fused_kernel(const u64_t* __restrict__ pk,
                                                          const float* __restrict__ emb,
                                                          const float* __restrict__ w,
                                                          const float* __restrict__ bias,
                                                          const float* __restrict__ src,
                                                          float* __restrict__ dst,
                                                          float* __restrict__ zp) {
    constexpr int IYB = (PN <= 4) ? PN : 8;   // cached iy-band height (tap span <=7)
    const int t   = threadIdx.x;          // 0..1023
    const int tx  = t & 31;
    const int co  = t >> 5;               // 0..31
    const int yt  = blockIdx.x & 7;
    const int b   = blockIdx.x >> 3;
    const int y0  = yt * 4;

    __shared__ float wl[32 * 32 * 9];     // 36.9 KB, [co][ci][9]
    __shared__ float til[16 * 6 * 34];    // 13.1 KB
    __shared__ int   idxg[PN * PN];       // winner indices for this b
    __shared__ int   riy[6][4];           // row bicubic windows (gy = y0-1..y0+4)
    __shared__ float rwy[6][4];
    __shared__ int   cix[34][4];          // col bicubic windows (gx = -1..32)
    __shared__ float cwx[34][4];
    // emb-row cache: [ch 16][iy band][ix + pad] — ch-major so tap reads
    // (lanes differ in ix) are bank-conflict-free; +1 pad de-conflicts writes.
    __shared__ float cache[16][IYB][PN + 1];

    for (int i = t; i < 32 * 32 * 9; i += 1024) wl[i] = w[i];
    // winner index grid for this batch image
    for (int i = t; i < PN * PN; i += 1024)
        idxg[i] = (int)(unsigned)(pk[b * PN * PN + i] & 0xFFFFFFFFull);
    // bicubic windows (computed by disjoint thread ranges -> parallel)
    const float scale = (float)PN / (float)HH;
    if (t < 6) {
        int r = t;
        int iy[4]; float wy[4];
        cubic_w(((float)(y0 - 1 + r) + 0.5f) * scale - 0.5f, PN, iy, wy);
#pragma unroll
        for (int a = 0; a < 4; a++) { riy[r][a] = iy[a]; rwy[r][a] = wy[a]; }
    }
    if (t >= 64 && t < 98) {
        int cl = t - 64;                  // col 0..33, gx = cl-1
        int ix[4]; float wx[4];
        cubic_w(((float)(cl - 1) + 0.5f) * scale - 0.5f, PN, ix, wx);
#pragma unroll
        for (int a = 0; a < 4; a++) { cix[cl][a] = ix[a]; cwx[cl][a] = wx[a]; }
    }

    // iy-band start: covers all clamped taps of gy in [y0-1, y0+4].
    // Computed redundantly per-thread (deterministic). For PN<=4 band = grid.
    int iy_lo = 0;
    if (PN > 4) {
        int lo = (int)floorf(((float)(y0 - 1) + 0.5f) * scale - 0.5f) - 1;
        if (lo < 0) lo = 0;
        if (lo > PN - IYB) lo = PN - IYB;
        iy_lo = lo;
    }

    float acc[4];
#pragma unroll
    for (int ry = 0; ry < 4; ry++) acc[ry] = bias[co];
    float hcv[4];

    for (int cc = 0; cc < 2; cc++) {
        __syncthreads();                  // idxg/windows ready (iter 0); til free
        // gather emb rows for this cc half into cache (coalesced: 16
        // consecutive ch floats per cell)
        for (int i = t; i < IYB * PN * 16; i += 1024) {
            int cil  = i & 15;
            int cell = i >> 4;
            int ix   = cell % PN;
            int iyb  = cell / PN;
            int idx  = idxg[(iy_lo + iyb) * PN + ix];
            cache[cil][iyb][ix] = emb[(size_t)idx * CH + cc * 16 + cil];
        }
        __syncthreads();
        // stage input: ci = cc*16 + 0..15, rows y0-1..y0+4, cols -1..32.
        // Each element is the bicubic upsample value (zero for pad), taps
        // read from the LDS cache (bit-identical values & fma order).
        for (int i = t; i < 16 * 6 * 34; i += 1024) {
            int col = i % 34;
            int row = (i / 34) % 6;
            int cil = i / 204;
            int gy = y0 - 1 + row;
            int gx = col - 1;
            float vv = 0.f;
            if ((unsigned)gy < 32u && (unsigned)gx < 32u) {
                float s = 0.f;
#pragma unroll
                for (int a = 0; a < 4; a++) {
                    const int iyb = riy[row][a] - iy_lo;
                    float rsum = 0.f;
#pragma unroll
                    for (int b2 = 0; b2 < 4; b2++) {
                        rsum = fmaf(cache[cil][iyb][cix[col][b2]],
                                    cwx[col][b2], rsum);
                    }
                    s = fmaf(rsum, rwy[row][a], s);
                }
                vv = s;
            }
            til[i] = vv;
        }
        __syncthreads();

        // capture h at this thread's own output positions (channel co) from LDS
        if (cc == (co >> 4)) {
#pragma unroll
            for (int ry = 0; ry < 4; ry++)
                hcv[ry] = til[(co & 15) * 204 + (ry + 1) * 34 + (tx + 1)];
        }

        for (int cil = 0; cil < 16; cil++) {
            float in[6][3];
            const float* tp = &til[cil * 204];
#pragma unroll
            for (int rr2 = 0; rr2 < 6; rr2++)
#pragma unroll
                for (int dx = 0; dx < 3; dx++)
                    in[rr2][dx] = tp[rr2 * 34 + tx + dx];
            // all 32 lanes of a half-wave share co -> LDS broadcast reads
            const float* wp = &wl[(co * 32 + cc * 16 + cil) * 9];
            float w0 = wp[0], w1 = wp[1], w2 = wp[2];
            float w3 = wp[3], w4 = wp[4], w5 = wp[5];
            float w6 = wp[6], w7 = wp[7], w8 = wp[8];
#pragma unroll
            for (int ry = 0; ry < 4; ry++) {
                float s = acc[ry];
                s = fmaf(in[ry + 0][0], w0, s);
                s = fmaf(in[ry + 0][1], w1, s);
                s = fmaf(in[ry + 0][2], w2, s);
                s = fmaf(in[ry + 1][0], w3, s);
                s = fmaf(in[ry + 1][1], w4, s);
                s = fmaf(in[ry + 1][2], w5, s);
                s = fmaf(in[ry + 2][0], w6, s);
                s = fmaf(in[ry + 2][1], w7, s);
                s = fmaf(in[ry + 2][2], w8, s);
                acc[ry] = s;
            }
        }
    }

    float pv[4];
#pragma unroll
    for (int ry = 0; ry < 4; ry++) {
        size_t off = (((size_t)(b * CH + co)) * HH + (y0 + ry)) * HH + tx;
        float dv = src[off] - (0.5f * hcv[ry] + 0.5f * acc[ry]);
        dst[off] = dv;
        pv[ry] = dv;
    }

    if constexpr (PN_NEXT != 0) {
        constexpr int PSP  = 32 / PN_NEXT;               // 16/8/4/2
        constexpr int NWY  = (PSP == 2) ? 2 : 1;         // windows along y in this block
        constexpr int ZSTR = BS * PN_NEXT * PN_NEXT * CH;
        float wsum[NWY];
#pragma unroll
        for (int k = 0; k < NWY; k++) wsum[k] = 0.f;
#pragma unroll
        for (int ry = 0; ry < 4; ry++) wsum[(NWY == 2) ? (ry >> 1) : 0] += pv[ry];
        // reduce across tx groups of PSP lanes (tx = lane&31, lane-minor;
        // m <= 16 < 32 keeps the xor within the same co half-wave)
#pragma unroll
        for (int m = 1; m < PSP; m <<= 1) {
#pragma unroll
            for (int k = 0; k < NWY; k++) wsum[k] += __shfl_xor(wsum[k], m, 64);
        }
        if ((tx & (PSP - 1)) == 0) {
            const int wx   = tx / PSP;
            const int slot = (PSP == 16) ? (yt & 3) : (PSP == 8) ? (yt & 1) : 0;
#pragma unroll
            for (int k = 0; k < NWY; k++) {
                const int wy = (PSP == 2) ? (yt * 2 + k) : (y0 / PSP);
                zp[(size_t)slot * ZSTR +
                   ((size_t)((b * PN_NEXT + wy) * PN_NEXT + wx)) * CH + co] = wsum[k];
            }
        }
    }
}

// ---------------------------------------------------------------------------
// hits bincount over all scales' packed winners (multi-block, parallel —
// r3 lesson: single-block LDS-hist finalize was a 60us serial tail; 171
// parallel blocks with global atomics never crack the top-5)
__global__ __launch_bounds__(256) void bincount_kernel(const u64_t* __restrict__ pk,
                                                       float* __restrict__ hits, int n) {
    int i = blockIdx.x * 256 + threadIdx.x;
    if (i < n) {
        int idx = (int)(unsigned)(pk[i] & 0xFFFFFFFFull);
        atomicAdd(&hits[idx], 1.0f);
    }
}

// ---------------------------------------------------------------------------
// perplexity + loss finalize (single block; reads only 4096-entry hist +
// 1024 lacc partials = 20 KB)
__global__ __launch_bounds__(256) void finalize_kernel(const float* __restrict__ hits,
                                                       const float* __restrict__ laccp,
                                                       float* __restrict__ outs) {
    __shared__ float sh[256];
    int t = threadIdx.x;
    // total = NROWS_TOTAL exactly (each row contributes one hit)
    const float tot = (float)NROWS_TOTAL;
    float ent = 0.f;
    for (int v = t; v < VV; v += 256) {
        float p = hits[v] / tot;
        ent += p * logf(p + 1e-10f);
    }
    sh[t] = ent;
    __syncthreads();
    for (int o = 128; o > 0; o >>= 1) {
        if (t < o) sh[t] += sh[t + o];
        __syncthreads();
    }
    float entT = sh[0];            // valid for all after the synced tree
    __syncthreads();
    float ls = 0.f;
    for (int i = t; i < 1024; i += 256) ls += laccp[i];
    sh[t] = ls;
    __syncthreads();
    for (int o = 128; o > 0; o >>= 1) {
        if (t < o) sh[t] += sh[t + o];
        __syncthreads();
    }
    if (t == 0) {
        // loss = SN*(1+BETA)*mean(f^2) = 7.5 * sumsq / 1048576  (f_hat stays 0)
        outs[0] = 7.5f * sh[0] * (1.0f / (float)FELEMS);
        outs[1] = expf(-entT);
    }
}

// ---------------------------------------------------------------------------
extern "C" void kernel_launch(void* const* d_in, const int* in_sizes, int n_in,
                              void* d_out, int out_size, void* d_ws, size_t ws_size,
                              hipStream_t stream) {
    const float* f   = (const float*)d_in[0];   // (32,32,32,32)
    const float* emb = (const float*)d_in[1];   // (4096,32)
    const float* phw = (const float*)d_in[2];   // (4,32,32,3,3)
    const float* phb = (const float*)d_in[3];   // (4,32)
    float* out = (float*)d_out;                 // f_hat (1048576) + loss + perplexity

    float* ws      = (float*)d_ws;
    float* hits    = ws;                              // [0, 4096)
    float* laccp   = ws + 4096;                       // [4096, 5120) partials
    u64_t* pkbase  = (u64_t*)(ws + 8448);             // 43680 u64 -> [8448, 95808)
    float* frest   = ws + 95808;                      // [95808, 1144384)
    half_t* zhi    = (half_t*)(ws + 1144384);         // si=0 z-split (1024 used)
    half_t* zlo    = (half_t*)(ws + 1275456);
    float* nesqh   = ws + 1537600;                    // [1537600, 1541696)
    half_t* ehi    = (half_t*)(ws + 2590272);         // 131072 halves = 65536 f
    half_t* elo    = (half_t*)(ws + 2655808);         // ends 2721344
    float* zp      = ws + 2721344;                    // 262144 f -> ends 2983488 (11.9 MB)

    // prep: emb split + nesqh + zero f_hat/hits + pk=+inf + pool si=0 + lacc
    prep_kernel<<<1024, 256, 0, stream>>>(f, emb, ehi, elo, nesqh, hits, laccp,
                                          zhi, zlo, pkbase, out);

    const int pkoff[6] = {0, 32, 160, 672, 2720, 10912};
    const size_t WSTR = (size_t)CH * CH * 9;          // 9216 per phi

    // si=0 (pn=1, sel=0): argmin from prep's z-split; conv pools for pn=2 (4 slots)
    argmin_stage<1, 16><<<dim3(2, 16), 256, 0, stream>>>(zhi, zlo, ehi, elo, nesqh,
                                                         pkbase + pkoff[0]);
    conv_fused_kernel<1, 2><<<256, 1024, 0, stream>>>(pkbase + pkoff[0], emb,
                                                      phw + 0 * WSTR, phb + 0 * CH,
                                                      f, frest, zp);

    // si=1 (pn=2, sel=0): z from 4 fp32 partials; conv pools for pn=4 (2 slots)
    argmin_zp<1, 16, 4, 2><<<dim3(8, 16), 256, 0, stream>>>(zp, ehi, elo, nesqh,
                                                            pkbase + pkoff[1]);
    conv_fused_kernel<2, 4><<<256, 1024, 0, stream>>>(pkbase + pkoff[1], emb,
                                                      phw + 0 * WSTR, phb + 0 * CH,
                                                      frest, frest, zp);

    // si=2 (pn=4, sel=1): z from 2 partials; conv pools for pn=8 (1 slot)
    argmin_zp<1, 16, 2, 4><<<dim3(32, 16), 256, 0, stream>>>(zp, ehi, elo, nesqh,
                                                             pkbase + pkoff[2]);
    conv_fused_kernel<4, 8><<<256, 1024, 0, stream>>>(pkbase + pkoff[2], emb,
                                                      phw + 1 * WSTR, phb + 1 * CH,
                                                      frest, frest, zp);

    // si=3 (pn=8, sel=2): z from 1 partial; conv pools for pn=16 (1 slot)
    argmin_zp<1, 8, 1, 8><<<dim3(128, 8), 256, 0, stream>>>(zp, ehi, elo, nesqh,
                                                            pkbase + pkoff[3]);
    conv_fused_kernel<8, 16><<<256, 1024, 0, stream>>>(pkbase + pkoff[3], emb,
                                                       phw + 2 * WSTR, phb + 2 * CH,
                                                       frest, frest, zp);

    // si=4 (pn=16, sel=3): z from 1 partial; conv has no pooling (si=5 reads frest)
    argmin_zp<2, 4, 1, 16><<<dim3(256, 4), 256, 0, stream>>>(zp, ehi, elo, nesqh,
                                                             pkbase + pkoff[4]);
    conv_fused_kernel<16, 0><<<256, 1024, 0, stream>>>(pkbase + pkoff[4], emb,
                                                       phw + 3 * WSTR, phb + 3 * CH,
                                                       frest, frest, nullptr);

    // si=5 (pn=32, sel=3): fused identity-pool argmin straight from frest
    argmin5_fused<<<dim3(512, 2), 256, 0, stream>>>(frest, ehi, elo, nesqh,
                                                    pkbase + pkoff[5]);

    bincount_kernel<<<(NROWS_TOTAL + 255) / 256, 256, 0, stream>>>(pkbase, hits, NROWS_TOTAL);
    finalize_kernel<<<1, 256, 0, stream>>>(hits, laccp, out + (out_size - 2));
}

// Round 6
// 249.154 us; speedup vs baseline: 3.1608x; 1.2238x over previous
//
#include <hip/hip_runtime.h>
#include <math.h>
#include <float.h>

// Problem constants (B=32, C=32, H=W=32, V=4096)
#define BS    32
#define CH    32
#define HH    32
#define VV    4096
#define FELEMS (BS*CH*HH*HH)   // 1048576
#define NROWS_TOTAL 43680      // sum over scales of B*pn*pn

typedef unsigned short ushort_t;
typedef unsigned long long u64_t;
typedef _Float16 half_t;
typedef __attribute__((ext_vector_type(8))) _Float16 half8;
typedef __attribute__((ext_vector_type(4))) float floatx4;

// 2-way fp16 split: x ~= h + l, residual <= 2^-22 |x|
__device__ inline void split2(float x, half_t* h, half_t* l) {
    half_t hh = (half_t)x;
    float r = x - (float)hh;
    *h = hh;
    *l = (half_t)r;
}

// fp32 -> sortable-descending key32 (bigger score => smaller key)
__device__ inline unsigned score_key32(float s) {
    unsigned u = __builtin_bit_cast(unsigned, s);
    unsigned m = (u & 0x80000000u) ? ~u : (u | 0x80000000u);  // monotone asc
    return ~m;                                                 // desc
}

// ---------------------------------------------------------------------------
// prep (grid 1024x256): emb fp16-split + nesqh, zero f_hat output + hits,
// init pk keys to +inf, prepack conv weights into padded [phi][co][ci][12]
// (enables float4 weight loads in conv: r5's [9] packing forced 9 scalar
// ds_reads and put weights on the LDS critical path), AND pool si=0 with
// per-block sumsq partials.
__global__ __launch_bounds__(256) void prep_kernel(const float* __restrict__ f,
                                                   const float* __restrict__ emb,
                                                   const float* __restrict__ phw,
                                                   float* __restrict__ wpad,
                                                   half_t* __restrict__ ehi,
                                                   half_t* __restrict__ elo,
                                                   float* __restrict__ nesqh,
                                                   float* __restrict__ hits,
                                                   float* __restrict__ laccp,
                                                   half_t* __restrict__ zhi,
                                                   half_t* __restrict__ zlo,
                                                   u64_t* __restrict__ pk,
                                                   float* __restrict__ dout) {
    int gid = blockIdx.x * 256 + threadIdx.x;      // 262144 threads
    float4 z4 = {0.f, 0.f, 0.f, 0.f};
    *(float4*)(dout + (size_t)gid * 4) = z4;
    if (gid < VV) hits[gid] = 0.f;
    if (gid < NROWS_TOTAL) pk[gid] = ~0ull;        // +inf keys
    if (gid < 4 * 32 * 32 * 12) {                  // 49152 weight-pad slots
        int k = gid % 12;
        wpad[gid] = (k < 9) ? phw[(gid / 12) * 9 + k] : 0.f;
    }
    if (gid < VV) {
        int v = gid;
        const float* ep = emb + (size_t)v * CH;
        float s = 0.f;
        half_t h[CH], l[CH];
#pragma unroll
        for (int i = 0; i < CH; i++) {
            float e = ep[i];
            s = fmaf(e, e, s);
            split2(e, &h[i], &l[i]);
        }
        nesqh[v] = -0.5f * s;
#pragma unroll
        for (int q = 0; q < 4; q++) {
            half8 H, L;
#pragma unroll
            for (int k = 0; k < 8; k++) {
                H[k] = h[q * 8 + k];
                L[k] = l[q * 8 + k];
            }
            *(half8*)(ehi + (size_t)v * CH + q * 8) = H;
            *(half8*)(elo + (size_t)v * CH + q * 8) = L;
        }
    }

    // pool si=0: pair = blockIdx.x = b*32 + c; base = f + pair*1024
    const int pair = blockIdx.x;
    const float* base = f + (size_t)pair * 1024;
    float s = 0.f, s2 = 0.f;
    for (int p = threadIdx.x; p < 1024; p += 256) {
        float v = base[p];
        s += v;
        s2 = fmaf(v, v, s2);
    }
    __shared__ float sh[256], sh2[256];
    sh[threadIdx.x] = s;
    sh2[threadIdx.x] = s2;
    __syncthreads();
    for (int o = 128; o > 0; o >>= 1) {
        if (threadIdx.x < o) {
            sh[threadIdx.x]  += sh[threadIdx.x + o];
            sh2[threadIdx.x] += sh2[threadIdx.x + o];
        }
        __syncthreads();
    }
    if (threadIdx.x == 0) {
        split2(sh[0] * (1.0f / 1024.0f), &zhi[pair], &zlo[pair]);
        laccp[pair] = sh2[0];      // deterministic partial, summed in finalize
    }
}

// ---------------------------------------------------------------------------
// 3-MFMA fp16 score chain for one 16-row group vs one 16-code tile
// score = z.e - 0.5|e|^2 = ah.bh + ah.bl + al.bh  (al.bl <= 2^-22 dropped)
__device__ inline floatx4 score_chain(half8 ah, half8 al,
                                      half8 bh, half8 bl, floatx4 ehv) {
    floatx4 acc;
    acc = __builtin_amdgcn_mfma_f32_16x16x32_f16(ah, bh, ehv, 0, 0, 0);
    acc = __builtin_amdgcn_mfma_f32_16x16x32_f16(ah, bl, acc, 0, 0, 0);
    acc = __builtin_amdgcn_mfma_f32_16x16x32_f16(al, bh, acc, 0, 0, 0);
    return acc;
}

__device__ inline void sel4(const floatx4& acc, int v, float* best, int* bidx) {
#pragma unroll
    for (int r = 0; r < 4; r++) {
        // strict >: lane-local scan is increasing v -> keeps lowest v on tie
        if (acc[r] > best[r]) { best[r] = acc[r]; bidx[r] = v; }
    }
}

// argmin core (1-deep prefetch — the proven fastest of four structural
// variants: 2-deep pipe, VS ladders, pooled-stage all regressed or tied).
// Wave wv scans TPW v-tiles from t0+wv*TPW over RT 16-row tiles.
// Deferred-select interleave (RT>=2). Winner per row merged cross-block via
// packed-key atomicMin (max score, lowest idx on tie == jnp.argmin).
template <int RT, int TPW>
__device__ inline void argmin_body(const half8* a1, const half8* a2,
                                   const half_t* __restrict__ ehi,
                                   const half_t* __restrict__ elo,
                                   const float* __restrict__ nesqh,
                                   u64_t* __restrict__ pk, int row0, int t0) {
    const int tid  = threadIdx.x;
    const int wv   = tid >> 6;
    const int lane = tid & 63;
    const int col  = lane & 15;
    const int quad = lane >> 4;

    float best[RT][4];
    int   bidx[RT][4];
#pragma unroll
    for (int rt = 0; rt < RT; rt++)
#pragma unroll
        for (int r = 0; r < 4; r++) { best[rt][r] = -FLT_MAX; bidx[rt][r] = 0; }

    int t = t0 + wv * TPW;
    const int tend = t + TPW;

    // prefetch tile t
    size_t eoff = ((size_t)((t << 4) + col) << 5) + (quad << 3);
    half8 nb1 = *(const half8*)(ehi + eoff);
    half8 nb2 = *(const half8*)(elo + eoff);
    float neh = nesqh[(t << 4) + col];

    floatx4 acc[RT];
    int vprev = 0;
    if (RT > 1) acc[RT - 1] = floatx4{-FLT_MAX, -FLT_MAX, -FLT_MAX, -FLT_MAX};

    for (; t < tend; t++) {
        const half8 b1 = nb1, b2 = nb2;
        const floatx4 ehv = {neh, neh, neh, neh};
        const int vcur = (t << 4) + col;
        // prefetch t+1 (clamped) before consuming current
        const int tn = (t + 1 < tend) ? (t + 1) : t;
        const size_t eoff2 = ((size_t)((tn << 4) + col) << 5) + (quad << 3);
        nb1 = *(const half8*)(ehi + eoff2);
        nb2 = *(const half8*)(elo + eoff2);
        neh = nesqh[(tn << 4) + col];

        if (RT == 1) {
            acc[0] = score_chain(a1[0], a2[0], b1, b2, ehv);
            sel4(acc[0], vcur, best[0], bidx[0]);
        } else {
            acc[0] = score_chain(a1[0], a2[0], b1, b2, ehv);
            sel4(acc[RT - 1], vprev, best[RT - 1], bidx[RT - 1]);  // deferred
#pragma unroll
            for (int rt = 1; rt < RT; rt++) {
                acc[rt] = score_chain(a1[rt], a2[rt], b1, b2, ehv);
                sel4(acc[rt - 1], vcur, best[rt - 1], bidx[rt - 1]);
            }
            vprev = vcur;
        }
    }
    if (RT > 1) sel4(acc[RT - 1], vprev, best[RT - 1], bidx[RT - 1]);

    // reduce across the 16 cols (v within tile) of each quad group
#pragma unroll
    for (int m = 1; m < 16; m <<= 1) {
#pragma unroll
        for (int rt = 0; rt < RT; rt++)
#pragma unroll
            for (int r = 0; r < 4; r++) {
                float s2 = __shfl_xor(best[rt][r], m, 64);
                int   v2 = __shfl_xor(bidx[rt][r], m, 64);
                if (s2 > best[rt][r] ||
                    (s2 == best[rt][r] && v2 < bidx[rt][r])) {
                    best[rt][r] = s2; bidx[rt][r] = v2;
                }
            }
    }

    __shared__ float sbs[4 * RT * 16];
    __shared__ int   sbi[4 * RT * 16];
    if (col == 0) {
#pragma unroll
        for (int rt = 0; rt < RT; rt++)
#pragma unroll
            for (int r = 0; r < 4; r++) {
                int row = rt * 16 + (quad << 2) + r;
                sbs[wv * RT * 16 + row] = best[rt][r];
                sbi[wv * RT * 16 + row] = bidx[rt][r];
            }
    }
    __syncthreads();
    if (tid < RT * 16) {
        float s = sbs[tid];
        int   v = sbi[tid];
        for (int w = 1; w < 4; w++) {
            float s2 = sbs[w * RT * 16 + tid];
            int   v2 = sbi[w * RT * 16 + tid];
            if (s2 > s || (s2 == s && v2 < v)) { s = s2; v = v2; }
        }
        u64_t key = ((u64_t)score_key32(s) << 32) | (unsigned)v;
        atomicMin(pk + row0 + tid, key);
    }
}

// generic stage: z-splits from memory (si=0 only now). grid = (nRowBlocks, VS)
template <int RT, int VS>
__global__ __launch_bounds__(256) void argmin_stage(const half_t* __restrict__ zhi,
                                                    const half_t* __restrict__ zlo,
                                                    const half_t* __restrict__ ehi,
                                                    const half_t* __restrict__ elo,
                                                    const float* __restrict__ nesqh,
                                                    u64_t* __restrict__ pk) {
    const int lane = threadIdx.x & 63;
    const int col  = lane & 15;
    const int quad = lane >> 4;
    const int row0 = blockIdx.x * (16 * RT);

    half8 a1[RT], a2[RT];
#pragma unroll
    for (int rt = 0; rt < RT; rt++) {
        size_t off = ((size_t)(row0 + rt * 16 + col) << 5) + (quad << 3);
        a1[rt] = *(const half8*)(zhi + off);
        a2[rt] = *(const half8*)(zlo + off);
    }
    argmin_body<RT, 64 / VS>(a1, a2, ehi, elo, nesqh, pk,
                             row0, (int)blockIdx.y * (256 / VS));
}

// zp stage (si=1..4): pooled z comes as NSLOT fp32 partial sums written by the
// previous conv's epilogue. Sum partials in fixed slot order, scale by the
// exact power-of-two 1/ps'^2, split2 in-register. Row-coalesced loads
// (wave reads 16 contiguous 128B rows).
template <int RT, int VS, int NSLOT, int PN>
__global__ __launch_bounds__(256) void argmin_zp(const float* __restrict__ zp,
                                                 const half_t* __restrict__ ehi,
                                                 const half_t* __restrict__ elo,
                                                 const float* __restrict__ nesqh,
                                                 u64_t* __restrict__ pk) {
    const int lane = threadIdx.x & 63;
    const int col  = lane & 15;
    const int quad = lane >> 4;
    const int row0 = blockIdx.x * (16 * RT);
    constexpr int ZSTR = BS * PN * PN * CH;
    constexpr int PSP  = 32 / PN;
    const float scale = 1.0f / (float)(PSP * PSP);

    half8 a1[RT], a2[RT];
#pragma unroll
    for (int rt = 0; rt < RT; rt++) {
        const float* p = zp + (size_t)(row0 + rt * 16 + col) * CH + (quad << 3);
        float4 v0 = *(const float4*)p;
        float4 v1 = *(const float4*)(p + 4);
#pragma unroll
        for (int sl = 1; sl < NSLOT; sl++) {
            float4 u0 = *(const float4*)(p + (size_t)sl * ZSTR);
            float4 u1 = *(const float4*)(p + (size_t)sl * ZSTR + 4);
            v0.x += u0.x; v0.y += u0.y; v0.z += u0.z; v0.w += u0.w;
            v1.x += u1.x; v1.y += u1.y; v1.z += u1.z; v1.w += u1.w;
        }
        float s[8] = {v0.x, v0.y, v0.z, v0.w, v1.x, v1.y, v1.z, v1.w};
#pragma unroll
        for (int k = 0; k < 8; k++) {
            half_t h, l;
            split2(s[k] * scale, &h, &l);
            a1[rt][k] = h; a2[rt][k] = l;
        }
    }
    argmin_body<RT, 64 / VS>(a1, a2, ehi, elo, nesqh, pk,
                             row0, (int)blockIdx.y * (256 / VS));
}

// si=5 fused: pool is identity (pn=32) -> split2 straight from frest.
// grid = (512, 2): RT=4, VS=2, each wave scans 32 tiles. (r10/r14-proven;
// VS=4, 2-deep pipe, and external-pool variants all regressed or tied.)
__global__ __launch_bounds__(256) void argmin5_fused(const float* __restrict__ frest,
                                                     const half_t* __restrict__ ehi,
                                                     const half_t* __restrict__ elo,
                                                     const float* __restrict__ nesqh,
                                                     u64_t* __restrict__ pk) {
    const int lane = threadIdx.x & 63;
    const int col  = lane & 15;
    const int quad = lane >> 4;
    const int row0 = blockIdx.x * 64;   // RT=4

    half8 a1[4], a2[4];
#pragma unroll
    for (int rt = 0; rt < 4; rt++) {
        int n = row0 + rt * 16 + col;               // row = (b*32+i)*32+j
        int b = n >> 10, i = (n >> 5) & 31, j = n & 31;
        const float* p = frest + ((((size_t)(b * CH + quad * 8)) * HH + i) * HH + j);
#pragma unroll
        for (int k = 0; k < 8; k++) {
            half_t h, l;
            split2(p[(size_t)k * (HH * HH)], &h, &l);   // c stride = 1024
            a1[rt][k] = h; a2[rt][k] = l;
        }
    }
    argmin_body<4, 32>(a1, a2, ehi, elo, nesqh, pk,
                       row0, (int)blockIdx.y * 128);
}

// ---------------------------------------------------------------------------
// bicubic weights, a=-0.75, half-pixel, edge clamp (matches ref _bicubic_mat)
__device__ inline void cubic_w(float xs, int pn, int* ix, float* w) {
    const float a = -0.75f;
    float xf = floorf(xs);
    int x0 = (int)xf;
    float t = xs - xf;
#pragma unroll
    for (int j = -1; j <= 2; j++) {
        float d = fabsf(t - (float)j);
        float ww;
        if (d < 1.0f)      ww = ((a + 2.0f) * d - (a + 3.0f)) * d * d + 1.0f;
        else if (d < 2.0f) ww = ((a * d - 5.0f * a) * d + 8.0f * a) * d - 4.0f * a;
        else               ww = 0.0f;
        int xi = x0 + j;
        xi = xi < 0 ? 0 : (xi > pn - 1 ? pn - 1 : xi);
        ix[j + 1] = xi;
        w[j + 1]  = ww;
    }
}

// ---------------------------------------------------------------------------
// FUSED upsample + Phi + residual: dst = src - (0.5*h + 0.5*(conv3x3(h)+bias))
// h = bicubic_upsample(emb[winner_idx]) computed during LDS staging (taps
// from an LDS emb-cache, r3-proven). ONE 1024-thread block per (b,yt)
// computes all 32 co (r5-proven: staging once per tile). r6 CHANGE: weights
// come from the prepacked PADDED global buffer [co][ci][12] via float4 loads
// (2x dwordx4 + 1 dword VMEM, L1/L2-resident 49KB) — off the LDS pipe, which
// was the core loop's critical path (r5: 9 scalar ds_reads per cil).
// LDS now ~24KB. PN_NEXT != 0 pools dst for the next scale into zp slots.
template <int PN, int PN_NEXT>
__global__ __launch_bounds__(1024) void conv_fused_kernel(const u64_t* __restrict__ pk,
                                                          const float* __restrict__ emb,
                                                          const float* __restrict__ wpad,
                                                          const float* __restrict__ bias,
                                                          const float* __restrict__ src,
                                                          float* __restrict__ dst,
                                                          float* __restrict__ zp) {
    constexpr int IYB = (PN <= 4) ? PN : 8;   // cached iy-band height (tap span <=7)
    const int t   = threadIdx.x;          // 0..1023
    const int tx  = t & 31;
    const int co  = t >> 5;               // 0..31
    const int yt  = blockIdx.x & 7;
    const int b   = blockIdx.x >> 3;
    const int y0  = yt * 4;

    __shared__ float til[16 * 6 * 34];    // 13.1 KB
    __shared__ int   idxg[PN * PN];       // winner indices for this b
    __shared__ int   riy[6][4];           // row bicubic windows (gy = y0-1..y0+4)
    __shared__ float rwy[6][4];
    __shared__ int   cix[34][4];          // col bicubic windows (gx = -1..32)
    __shared__ float cwx[34][4];
    // emb-row cache: [ch 16][iy band][ix + pad] — ch-major so tap reads
    // (lanes differ in ix) are bank-conflict-free; +1 pad de-conflicts writes.
    __shared__ float cache[16][IYB][PN + 1];

    // winner index grid for this batch image
    for (int i = t; i < PN * PN; i += 1024)
        idxg[i] = (int)(unsigned)(pk[b * PN * PN + i] & 0xFFFFFFFFull);
    // bicubic windows (computed by disjoint thread ranges -> parallel)
    const float scale = (float)PN / (float)HH;
    if (t < 6) {
        int r = t;
        int iy[4]; float wy[4];
        cubic_w(((float)(y0 - 1 + r) + 0.5f) * scale - 0.5f, PN, iy, wy);
#pragma unroll
        for (int a = 0; a < 4; a++) { riy[r][a] = iy[a]; rwy[r][a] = wy[a]; }
    }
    if (t >= 64 && t < 98) {
        int cl = t - 64;                  // col 0..33, gx = cl-1
        int ix[4]; float wx[4];
        cubic_w(((float)(cl - 1) + 0.5f) * scale - 0.5f, PN, ix, wx);
#pragma unroll
        for (int a = 0; a < 4; a++) { cix[cl][a] = ix[a]; cwx[cl][a] = wx[a]; }
    }

    // iy-band start: covers all clamped taps of gy in [y0-1, y0+4].
    // Computed redundantly per-thread (deterministic). For PN<=4 band = grid.
    int iy_lo = 0;
    if (PN > 4) {
        int lo = (int)floorf(((float)(y0 - 1) + 0.5f) * scale - 0.5f) - 1;
        if (lo < 0) lo = 0;
        if (lo > PN - IYB) lo = PN - IYB;
        iy_lo = lo;
    }

    float acc[4];
#pragma unroll
    for (int ry = 0; ry < 4; ry++) acc[ry] = bias[co];
    float hcv[4];

    for (int cc = 0; cc < 2; cc++) {
        __syncthreads();                  // idxg/windows ready (iter 0); til free
        // gather emb rows for this cc half into cache (coalesced: 16
        // consecutive ch floats per cell)
        for (int i = t; i < IYB * PN * 16; i += 1024) {
            int cil  = i & 15;
            int cell = i >> 4;
            int ix   = cell % PN;
            int iyb  = cell / PN;
            int idx  = idxg[(iy_lo + iyb) * PN + ix];
            cache[cil][iyb][ix] = emb[(size_t)idx * CH + cc * 16 + cil];
        }
        __syncthreads();
        // stage input: ci = cc*16 + 0..15, rows y0-1..y0+4, cols -1..32.
        // Each element is the bicubic upsample value (zero for pad), taps
        // read from the LDS cache (bit-identical values & fma order).
        for (int i = t; i < 16 * 6 * 34; i += 1024) {
            int col = i % 34;
            int row = (i / 34) % 6;
            int cil = i / 204;
            int gy = y0 - 1 + row;
            int gx = col - 1;
            float vv = 0.f;
            if ((unsigned)gy < 32u && (unsigned)gx < 32u) {
                float s = 0.f;
#pragma unroll
                for (int a = 0; a < 4; a++) {
                    const int iyb = riy[row][a] - iy_lo;
                    float rsum = 0.f;
#pragma unroll
                    for (int b2 = 0; b2 < 4; b2++) {
                        rsum = fmaf(cache[cil][iyb][cix[col][b2]],
                                    cwx[col][b2], rsum);
                    }
                    s = fmaf(rsum, rwy[row][a], s);
                }
                vv = s;
            }
            til[i] = vv;
        }
        __syncthreads();

        // capture h at this thread's own output positions (channel co) from LDS
        if (cc == (co >> 4)) {
#pragma unroll
            for (int ry = 0; ry < 4; ry++)
                hcv[ry] = til[(co & 15) * 204 + (ry + 1) * 34 + (tx + 1)];
        }

        for (int cil = 0; cil < 16; cil++) {
            float in[6][3];
            const float* tp = &til[cil * 204];
#pragma unroll
            for (int rr2 = 0; rr2 < 6; rr2++)
#pragma unroll
                for (int dx = 0; dx < 3; dx++)
                    in[rr2][dx] = tp[rr2 * 34 + tx + dx];
            // weights from padded global (L1/L2-resident; off the LDS pipe)
            const float* wp = wpad + (size_t)(co * 32 + cc * 16 + cil) * 12;
            float4 wa = *(const float4*)wp;
            float4 wb = *(const float4*)(wp + 4);
            float  w8 = wp[8];
#pragma unroll
            for (int ry = 0; ry < 4; ry++) {
                float s = acc[ry];
                s = fmaf(in[ry + 0][0], wa.x, s);
                s = fmaf(in[ry + 0][1], wa.y, s);
                s = fmaf(in[ry + 0][2], wa.z, s);
                s = fmaf(in[ry + 1][0], wa.w, s);
                s = fmaf(in[ry + 1][1], wb.x, s);
                s = fmaf(in[ry + 1][2], wb.y, s);
                s = fmaf(in[ry + 2][0], wb.z, s);
                s = fmaf(in[ry + 2][1], wb.w, s);
                s = fmaf(in[ry + 2][2], w8,   s);
                acc[ry] = s;
            }
        }
    }

    float pv[4];
#pragma unroll
    for (int ry = 0; ry < 4; ry++) {
        size_t off = (((size_t)(b * CH + co)) * HH + (y0 + ry)) * HH + tx;
        float dv = src[off] - (0.5f * hcv[ry] + 0.5f * acc[ry]);
        dst[off] = dv;
        pv[ry] = dv;
    }

    if constexpr (PN_NEXT != 0) {
        constexpr int PSP  = 32 / PN_NEXT;               // 16/8/4/2
        constexpr int NWY  = (PSP == 2) ? 2 : 1;         // windows along y in this block
        constexpr int ZSTR = BS * PN_NEXT * PN_NEXT * CH;
        float wsum[NWY];
#pragma unroll
        for (int k = 0; k < NWY; k++) wsum[k] = 0.f;
#pragma unroll
        for (int ry = 0; ry < 4; ry++) wsum[(NWY == 2) ? (ry >> 1) : 0] += pv[ry];
        // reduce across tx groups of PSP lanes (tx = lane&31, lane-minor;
        // m <= 16 < 32 keeps the xor within the same co half-wave)
#pragma unroll
        for (int m = 1; m < PSP; m <<= 1) {
#pragma unroll
            for (int k = 0; k < NWY; k++) wsum[k] += __shfl_xor(wsum[k], m, 64);
        }
        if ((tx & (PSP - 1)) == 0) {
            const int wx   = tx / PSP;
            const int slot = (PSP == 16) ? (yt & 3) : (PSP == 8) ? (yt & 1) : 0;
#pragma unroll
            for (int k = 0; k < NWY; k++) {
                const int wy = (PSP == 2) ? (yt * 2 + k) : (y0 / PSP);
                zp[(size_t)slot * ZSTR +
                   ((size_t)((b * PN_NEXT + wy) * PN_NEXT + wx)) * CH + co] = wsum[k];
            }
        }
    }
}

// ---------------------------------------------------------------------------
// hits bincount over all scales' packed winners (multi-block, parallel —
// r3 lesson: single-block LDS-hist finalize was a 60us serial tail; 171
// parallel blocks with global atomics never crack the top-5)
__global__ __launch_bounds__(256) void bincount_kernel(const u64_t* __restrict__ pk,
                                                       float* __restrict__ hits, int n) {
    int i = blockIdx.x * 256 + threadIdx.x;
    if (i < n) {
        int idx = (int)(unsigned)(pk[i] & 0xFFFFFFFFull);
        atomicAdd(&hits[idx], 1.0f);
    }
}

// ---------------------------------------------------------------------------
// perplexity + loss finalize (single block; reads only 4096-entry hist +
// 1024 lacc partials = 20 KB)
__global__ __launch_bounds__(256) void finalize_kernel(const float* __restrict__ hits,
                                                       const float* __restrict__ laccp,
                                                       float* __restrict__ outs) {
    __shared__ float sh[256];
    int t = threadIdx.x;
    // total = NROWS_TOTAL exactly (each row contributes one hit)
    const float tot = (float)NROWS_TOTAL;
    float ent = 0.f;
    for (int v = t; v < VV; v += 256) {
        float p = hits[v] / tot;
        ent += p * logf(p + 1e-10f);
    }
    sh[t] = ent;
    __syncthreads();
    for (int o = 128; o > 0; o >>= 1) {
        if (t < o) sh[t] += sh[t + o];
        __syncthreads();
    }
    float entT = sh[0];            // valid for all after the synced tree
    __syncthreads();
    float ls = 0.f;
    for (int i = t; i < 1024; i += 256) ls += laccp[i];
    sh[t] = ls;
    __syncthreads();
    for (int o = 128; o > 0; o >>= 1) {
        if (t < o) sh[t] += sh[t + o];
        __syncthreads();
    }
    if (t == 0) {
        // loss = SN*(1+BETA)*mean(f^2) = 7.5 * sumsq / 1048576  (f_hat stays 0)
        outs[0] = 7.5f * sh[0] * (1.0f / (float)FELEMS);
        outs[1] = expf(-entT);
    }
}

// ---------------------------------------------------------------------------
extern "C" void kernel_launch(void* const* d_in, const int* in_sizes, int n_in,
                              void* d_out, int out_size, void* d_ws, size_t ws_size,
                              hipStream_t stream) {
    const float* f   = (const float*)d_in[0];   // (32,32,32,32)
    const float* emb = (const float*)d_in[1];   // (4096,32)
    const float* phw = (const float*)d_in[2];   // (4,32,32,3,3)
    const float* phb = (const float*)d_in[3];   // (4,32)
    float* out = (float*)d_out;                 // f_hat (1048576) + loss + perplexity

    float* ws      = (float*)d_ws;
    float* hits    = ws;                              // [0, 4096)
    float* laccp   = ws + 4096;                       // [4096, 5120) partials
    u64_t* pkbase  = (u64_t*)(ws + 8448);             // 43680 u64 -> [8448, 95808)
    float* frest   = ws + 95808;                      // [95808, 1144384)
    half_t* zhi    = (half_t*)(ws + 1144384);         // si=0 z-split (1024 used)
    half_t* zlo    = (half_t*)(ws + 1275456);
    float* nesqh   = ws + 1537600;                    // [1537600, 1541696)
    half_t* ehi    = (half_t*)(ws + 2590272);         // 131072 halves = 65536 f
    half_t* elo    = (half_t*)(ws + 2655808);         // ends 2721344
    float* zp      = ws + 2721344;                    // 262144 f -> ends 2983488
    float* wpad    = ws + 2983488;                    // 49152 f -> ends 3032640 (12.1 MB)

    // prep: emb split + nesqh + zero f_hat/hits + pk=+inf + wpad + pool si=0
    prep_kernel<<<1024, 256, 0, stream>>>(f, emb, phw, wpad, ehi, elo, nesqh,
                                          hits, laccp, zhi, zlo, pkbase, out);

    const int pkoff[6] = {0, 32, 160, 672, 2720, 10912};
    const size_t WP = (size_t)32 * 32 * 12;           // 12288 per phi (padded)

    // si=0 (pn=1, sel=0): argmin from prep's z-split; conv pools for pn=2 (4 slots)
    argmin_stage<1, 16><<<dim3(2, 16), 256, 0, stream>>>(zhi, zlo, ehi, elo, nesqh,
                                                         pkbase + pkoff[0]);
    conv_fused_kernel<1, 2><<<256, 1024, 0, stream>>>(pkbase + pkoff[0], emb,
                                                      wpad + 0 * WP, phb + 0 * CH,
                                                      f, frest, zp);

    // si=1 (pn=2, sel=0): z from 4 fp32 partials; conv pools for pn=4 (2 slots)
    argmin_zp<1, 16, 4, 2><<<dim3(8, 16), 256, 0, stream>>>(zp, ehi, elo, nesqh,
                                                            pkbase + pkoff[1]);
    conv_fused_kernel<2, 4><<<256, 1024, 0, stream>>>(pkbase + pkoff[1], emb,
                                                      wpad + 0 * WP, phb + 0 * CH,
                                                      frest, frest, zp);

    // si=2 (pn=4, sel=1): z from 2 partials; conv pools for pn=8 (1 slot)
    argmin_zp<1, 16, 2, 4><<<dim3(32, 16), 256, 0, stream>>>(zp, ehi, elo, nesqh,
                                                             pkbase + pkoff[2]);
    conv_fused_kernel<4, 8><<<256, 1024, 0, stream>>>(pkbase + pkoff[2], emb,
                                                      wpad + 1 * WP, phb + 1 * CH,
                                                      frest, frest, zp);

    // si=3 (pn=8, sel=2): z from 1 partial; conv pools for pn=16 (1 slot)
    argmin_zp<1, 8, 1, 8><<<dim3(128, 8), 256, 0, stream>>>(zp, ehi, elo, nesqh,
                                                            pkbase + pkoff[3]);
    conv_fused_kernel<8, 16><<<256, 1024, 0, stream>>>(pkbase + pkoff[3], emb,
                                                       wpad + 2 * WP, phb + 2 * CH,
                                                       frest, frest, zp);

    // si=4 (pn=16, sel=3): z from 1 partial; conv has no pooling (si=5 reads frest)
    argmin_zp<2, 4, 1, 16><<<dim3(256, 4), 256, 0, stream>>>(zp, ehi, elo, nesqh,
                                                             pkbase + pkoff[4]);
    conv_fused_kernel<16, 0><<<256, 1024, 0, stream>>>(pkbase + pkoff[4], emb,
                                                       wpad + 3 * WP, phb + 3 * CH,
                                                       frest, frest, nullptr);

    // si=5 (pn=32, sel=3): fused identity-pool argmin straight from frest
    argmin5_fused<<<dim3(512, 2), 256, 0, stream>>>(frest, ehi, elo, nesqh,
                                                    pkbase + pkoff[5]);

    bincount_kernel<<<(NROWS_TOTAL + 255) / 256, 256, 0, stream>>>(pkbase, hits, NROWS_TOTAL);
    finalize_kernel<<<1, 256, 0, stream>>>(hits, laccp, out + (out_size - 2));
}

// Round 7
// 202.812 us; speedup vs baseline: 3.8831x; 1.2285x over previous
//
#include <hip/hip_runtime.h>
#include <math.h>
#include <float.h>

// Problem constants (B=32, C=32, H=W=32, V=4096)
#define BS    32
#define CH    32
#define HH    32
#define VV    4096
#define FELEMS (BS*CH*HH*HH)   // 1048576
#define NROWS_TOTAL 43680      // sum over scales of B*pn*pn

typedef unsigned short ushort_t;
typedef unsigned long long u64_t;
typedef _Float16 half_t;
typedef __attribute__((ext_vector_type(8))) _Float16 half8;
typedef __attribute__((ext_vector_type(4))) float floatx4;

// 2-way fp16 split: x ~= h + l, residual <= 2^-22 |x|
__device__ inline void split2(float x, half_t* h, half_t* l) {
    half_t hh = (half_t)x;
    float r = x - (float)hh;
    *h = hh;
    *l = (half_t)r;
}

// fp32 -> sortable-descending key32 (bigger score => smaller key)
__device__ inline unsigned score_key32(float s) {
    unsigned u = __builtin_bit_cast(unsigned, s);
    unsigned m = (u & 0x80000000u) ? ~u : (u | 0x80000000u);  // monotone asc
    return ~m;                                                 // desc
}

// ---------------------------------------------------------------------------
// prep (grid 1024x256): emb fp16-split + nesqh, zero f_hat output + hits +
// zp pool-accumulators, init pk keys to +inf, split conv weights into
// MFMA-A-fragment-ordered global buffers (lane col=co, 8 ci per quad),
// AND pool si=0 with per-block sumsq partials.
__global__ __launch_bounds__(256) void prep_kernel(const float* __restrict__ f,
                                                   const float* __restrict__ emb,
                                                   const float* __restrict__ phw,
                                                   half_t* __restrict__ whi,
                                                   half_t* __restrict__ wlo,
                                                   half_t* __restrict__ ehi,
                                                   half_t* __restrict__ elo,
                                                   float* __restrict__ nesqh,
                                                   float* __restrict__ hits,
                                                   float* __restrict__ laccp,
                                                   half_t* __restrict__ zhi,
                                                   half_t* __restrict__ zlo,
                                                   u64_t* __restrict__ pk,
                                                   float* __restrict__ zpbase,
                                                   float* __restrict__ dout) {
    int gid = blockIdx.x * 256 + threadIdx.x;      // 262144 threads
    float4 z4 = {0.f, 0.f, 0.f, 0.f};
    *(float4*)(dout + (size_t)gid * 4) = z4;
    if (gid < VV) hits[gid] = 0.f;
    if (gid < NROWS_TOTAL) pk[gid] = ~0ull;        // +inf keys
    for (int j = gid; j < 348160; j += 262144) zpbase[j] = 0.f;  // pool accum
    if (gid < 36864) {
        // W split-frag pack: idx = ((((phi*2+mt)*9+tau)*4+q)*16+c)*8+k
        int k = gid & 7, c = (gid >> 3) & 15, q = (gid >> 7) & 3;
        int t2 = gid >> 9;                 // 0..71
        int tau = t2 % 9, m2 = t2 / 9;
        int mt = m2 & 1, phi = m2 >> 1;
        int co = mt * 16 + c, ci = q * 8 + k;
        float w = phw[((size_t)(phi * 32 + co) * 32 + ci) * 9 + tau];
        half_t h, l; split2(w, &h, &l);
        whi[gid] = h; wlo[gid] = l;
    }
    if (gid < VV) {
        int v = gid;
        const float* ep = emb + (size_t)v * CH;
        float s = 0.f;
        half_t h[CH], l[CH];
#pragma unroll
        for (int i = 0; i < CH; i++) {
            float e = ep[i];
            s = fmaf(e, e, s);
            split2(e, &h[i], &l[i]);
        }
        nesqh[v] = -0.5f * s;
#pragma unroll
        for (int q = 0; q < 4; q++) {
            half8 H, L;
#pragma unroll
            for (int k = 0; k < 8; k++) {
                H[k] = h[q * 8 + k];
                L[k] = l[q * 8 + k];
            }
            *(half8*)(ehi + (size_t)v * CH + q * 8) = H;
            *(half8*)(elo + (size_t)v * CH + q * 8) = L;
        }
    }

    // pool si=0: pair = blockIdx.x = b*32 + c; base = f + pair*1024
    const int pair = blockIdx.x;
    const float* base = f + (size_t)pair * 1024;
    float s = 0.f, s2 = 0.f;
    for (int p = threadIdx.x; p < 1024; p += 256) {
        float v = base[p];
        s += v;
        s2 = fmaf(v, v, s2);
    }
    __shared__ float sh[256], sh2[256];
    sh[threadIdx.x] = s;
    sh2[threadIdx.x] = s2;
    __syncthreads();
    for (int o = 128; o > 0; o >>= 1) {
        if (threadIdx.x < o) {
            sh[threadIdx.x]  += sh[threadIdx.x + o];
            sh2[threadIdx.x] += sh2[threadIdx.x + o];
        }
        __syncthreads();
    }
    if (threadIdx.x == 0) {
        split2(sh[0] * (1.0f / 1024.0f), &zhi[pair], &zlo[pair]);
        laccp[pair] = sh2[0];      // deterministic partial, summed in finalize
    }
}

// ---------------------------------------------------------------------------
// 3-MFMA fp16 score chain for one 16-row group vs one 16-code tile
// score = z.e - 0.5|e|^2 = ah.bh + ah.bl + al.bh  (al.bl <= 2^-22 dropped)
__device__ inline floatx4 score_chain(half8 ah, half8 al,
                                      half8 bh, half8 bl, floatx4 ehv) {
    floatx4 acc;
    acc = __builtin_amdgcn_mfma_f32_16x16x32_f16(ah, bh, ehv, 0, 0, 0);
    acc = __builtin_amdgcn_mfma_f32_16x16x32_f16(ah, bl, acc, 0, 0, 0);
    acc = __builtin_amdgcn_mfma_f32_16x16x32_f16(al, bh, acc, 0, 0, 0);
    return acc;
}

__device__ inline void sel4(const floatx4& acc, int v, float* best, int* bidx) {
#pragma unroll
    for (int r = 0; r < 4; r++) {
        // strict >: lane-local scan is increasing v -> keeps lowest v on tie
        if (acc[r] > best[r]) { best[r] = acc[r]; bidx[r] = v; }
    }
}

// argmin core (1-deep prefetch — the proven fastest of four structural
// variants). Wave wv scans TPW v-tiles from t0+wv*TPW over RT 16-row tiles.
// Winner per row merged cross-block via packed-key atomicMin.
template <int RT, int TPW>
__device__ inline void argmin_body(const half8* a1, const half8* a2,
                                   const half_t* __restrict__ ehi,
                                   const half_t* __restrict__ elo,
                                   const float* __restrict__ nesqh,
                                   u64_t* __restrict__ pk, int row0, int t0) {
    const int tid  = threadIdx.x;
    const int wv   = tid >> 6;
    const int lane = tid & 63;
    const int col  = lane & 15;
    const int quad = lane >> 4;

    float best[RT][4];
    int   bidx[RT][4];
#pragma unroll
    for (int rt = 0; rt < RT; rt++)
#pragma unroll
        for (int r = 0; r < 4; r++) { best[rt][r] = -FLT_MAX; bidx[rt][r] = 0; }

    int t = t0 + wv * TPW;
    const int tend = t + TPW;

    // prefetch tile t
    size_t eoff = ((size_t)((t << 4) + col) << 5) + (quad << 3);
    half8 nb1 = *(const half8*)(ehi + eoff);
    half8 nb2 = *(const half8*)(elo + eoff);
    float neh = nesqh[(t << 4) + col];

    floatx4 acc[RT];
    int vprev = 0;
    if (RT > 1) acc[RT - 1] = floatx4{-FLT_MAX, -FLT_MAX, -FLT_MAX, -FLT_MAX};

    for (; t < tend; t++) {
        const half8 b1 = nb1, b2 = nb2;
        const floatx4 ehv = {neh, neh, neh, neh};
        const int vcur = (t << 4) + col;
        // prefetch t+1 (clamped) before consuming current
        const int tn = (t + 1 < tend) ? (t + 1) : t;
        const size_t eoff2 = ((size_t)((tn << 4) + col) << 5) + (quad << 3);
        nb1 = *(const half8*)(ehi + eoff2);
        nb2 = *(const half8*)(elo + eoff2);
        neh = nesqh[(tn << 4) + col];

        if (RT == 1) {
            acc[0] = score_chain(a1[0], a2[0], b1, b2, ehv);
            sel4(acc[0], vcur, best[0], bidx[0]);
        } else {
            acc[0] = score_chain(a1[0], a2[0], b1, b2, ehv);
            sel4(acc[RT - 1], vprev, best[RT - 1], bidx[RT - 1]);  // deferred
#pragma unroll
            for (int rt = 1; rt < RT; rt++) {
                acc[rt] = score_chain(a1[rt], a2[rt], b1, b2, ehv);
                sel4(acc[rt - 1], vcur, best[rt - 1], bidx[rt - 1]);
            }
            vprev = vcur;
        }
    }
    if (RT > 1) sel4(acc[RT - 1], vprev, best[RT - 1], bidx[RT - 1]);

    // reduce across the 16 cols (v within tile) of each quad group
#pragma unroll
    for (int m = 1; m < 16; m <<= 1) {
#pragma unroll
        for (int rt = 0; rt < RT; rt++)
#pragma unroll
            for (int r = 0; r < 4; r++) {
                float s2 = __shfl_xor(best[rt][r], m, 64);
                int   v2 = __shfl_xor(bidx[rt][r], m, 64);
                if (s2 > best[rt][r] ||
                    (s2 == best[rt][r] && v2 < bidx[rt][r])) {
                    best[rt][r] = s2; bidx[rt][r] = v2;
                }
            }
    }

    __shared__ float sbs[4 * RT * 16];
    __shared__ int   sbi[4 * RT * 16];
    if (col == 0) {
#pragma unroll
        for (int rt = 0; rt < RT; rt++)
#pragma unroll
            for (int r = 0; r < 4; r++) {
                int row = rt * 16 + (quad << 2) + r;
                sbs[wv * RT * 16 + row] = best[rt][r];
                sbi[wv * RT * 16 + row] = bidx[rt][r];
            }
    }
    __syncthreads();
    if (tid < RT * 16) {
        float s = sbs[tid];
        int   v = sbi[tid];
        for (int w = 1; w < 4; w++) {
            float s2 = sbs[w * RT * 16 + tid];
            int   v2 = sbi[w * RT * 16 + tid];
            if (s2 > s || (s2 == s && v2 < v)) { s = s2; v = v2; }
        }
        u64_t key = ((u64_t)score_key32(s) << 32) | (unsigned)v;
        atomicMin(pk + row0 + tid, key);
    }
}

// generic stage: z-splits from memory (si=0 only). grid = (nRowBlocks, VS)
template <int RT, int VS>
__global__ __launch_bounds__(256) void argmin_stage(const half_t* __restrict__ zhi,
                                                    const half_t* __restrict__ zlo,
                                                    const half_t* __restrict__ ehi,
                                                    const half_t* __restrict__ elo,
                                                    const float* __restrict__ nesqh,
                                                    u64_t* __restrict__ pk) {
    const int lane = threadIdx.x & 63;
    const int col  = lane & 15;
    const int quad = lane >> 4;
    const int row0 = blockIdx.x * (16 * RT);

    half8 a1[RT], a2[RT];
#pragma unroll
    for (int rt = 0; rt < RT; rt++) {
        size_t off = ((size_t)(row0 + rt * 16 + col) << 5) + (quad << 3);
        a1[rt] = *(const half8*)(zhi + off);
        a2[rt] = *(const half8*)(zlo + off);
    }
    argmin_body<RT, 64 / VS>(a1, a2, ehi, elo, nesqh, pk,
                             row0, (int)blockIdx.y * (256 / VS));
}

// zp stage (si=1..4): pooled z arrives fully accumulated (conv epilogue
// atomicAdds into a zeroed per-scale slice). Scale by exact pow2 1/ps'^2,
// split2 in-register.
template <int RT, int VS, int PN>
__global__ __launch_bounds__(256) void argmin_zp(const float* __restrict__ zp,
                                                 const half_t* __restrict__ ehi,
                                                 const half_t* __restrict__ elo,
                                                 const float* __restrict__ nesqh,
                                                 u64_t* __restrict__ pk) {
    const int lane = threadIdx.x & 63;
    const int col  = lane & 15;
    const int quad = lane >> 4;
    const int row0 = blockIdx.x * (16 * RT);
    constexpr int PSP = 32 / PN;
    const float scale = 1.0f / (float)(PSP * PSP);

    half8 a1[RT], a2[RT];
#pragma unroll
    for (int rt = 0; rt < RT; rt++) {
        const float* p = zp + (size_t)(row0 + rt * 16 + col) * CH + (quad << 3);
        float4 v0 = *(const float4*)p;
        float4 v1 = *(const float4*)(p + 4);
        float s[8] = {v0.x, v0.y, v0.z, v0.w, v1.x, v1.y, v1.z, v1.w};
#pragma unroll
        for (int k = 0; k < 8; k++) {
            half_t h, l;
            split2(s[k] * scale, &h, &l);
            a1[rt][k] = h; a2[rt][k] = l;
        }
    }
    argmin_body<RT, 64 / VS>(a1, a2, ehi, elo, nesqh, pk,
                             row0, (int)blockIdx.y * (256 / VS));
}

// si=5 fused: pool is identity (pn=32) -> split2 straight from frest.
__global__ __launch_bounds__(256) void argmin5_fused(const float* __restrict__ frest,
                                                     const half_t* __restrict__ ehi,
                                                     const half_t* __restrict__ elo,
                                                     const float* __restrict__ nesqh,
                                                     u64_t* __restrict__ pk) {
    const int lane = threadIdx.x & 63;
    const int col  = lane & 15;
    const int quad = lane >> 4;
    const int row0 = blockIdx.x * 64;   // RT=4

    half8 a1[4], a2[4];
#pragma unroll
    for (int rt = 0; rt < 4; rt++) {
        int n = row0 + rt * 16 + col;               // row = (b*32+i)*32+j
        int b = n >> 10, i = (n >> 5) & 31, j = n & 31;
        const float* p = frest + ((((size_t)(b * CH + quad * 8)) * HH + i) * HH + j);
#pragma unroll
        for (int k = 0; k < 8; k++) {
            half_t h, l;
            split2(p[(size_t)k * (HH * HH)], &h, &l);   // c stride = 1024
            a1[rt][k] = h; a2[rt][k] = l;
        }
    }
    argmin_body<4, 32>(a1, a2, ehi, elo, nesqh, pk,
                       row0, (int)blockIdx.y * 128);
}

// ---------------------------------------------------------------------------
// bicubic weights, a=-0.75, half-pixel, edge clamp (matches ref _bicubic_mat)
__device__ inline void cubic_w(float xs, int pn, int* ix, float* w) {
    const float a = -0.75f;
    float xf = floorf(xs);
    int x0 = (int)xf;
    float t = xs - xf;
#pragma unroll
    for (int j = -1; j <= 2; j++) {
        float d = fabsf(t - (float)j);
        float ww;
        if (d < 1.0f)      ww = ((a + 2.0f) * d - (a + 3.0f)) * d * d + 1.0f;
        else if (d < 2.0f) ww = ((a * d - 5.0f * a) * d + 8.0f * a) * d - 4.0f * a;
        else               ww = 0.0f;
        int xi = x0 + j;
        xi = xi < 0 ? 0 : (xi > pn - 1 ? pn - 1 : xi);
        ix[j + 1] = xi;
        w[j + 1]  = ww;
    }
}

// ---------------------------------------------------------------------------
// MFMA conv: dst = src - (0.5*h + 0.5*(conv3x3(h)+bias)), h = bicubic
// upsample (bit-identical fp32 chain), fp16-split into LDS, consumed by
// 16x16x32 f16 MFMA 3-chains (same split scheme as argmin; wh.hh+wh.hl+wl.hh).
// Fragment convention mirrors the PROVEN argmin kernel: A lane-col = out-row
// (co), B lane-col = out-col (pix), C row=(quad*4+r), col=lane&15.
// Block = (b, yt): 1024 thr = 16 waves; wave wid: mt=wid&1 (co 16-block),
// Nt=wid>>1 -> ty=Nt>>1 (row y0+ty), xh=Nt&1 (x 16-block). 27 MFMA/wave.
// H layout [6 rows][34 cols][32 ch] ch-minor: B-frag = aligned half8; 9 taps
// = shifted bases; quad fills 16B gaps -> conflict-free.
// PN_NEXT != 0: pool epilogue shfl-reduces x-windows and atomicAdds into the
// zeroed per-scale zp slice (argmin_zp scales by 1/PSP^2).
template <int PN, int PN_NEXT>
__global__ __launch_bounds__(1024) void conv_mfma_kernel(const u64_t* __restrict__ pk,
                                                         const float* __restrict__ emb,
                                                         const half_t* __restrict__ whi,
                                                         const half_t* __restrict__ wlo,
                                                         const float* __restrict__ bias,
                                                         const float* __restrict__ src,
                                                         float* __restrict__ dst,
                                                         float* __restrict__ zp) {
    constexpr int IYB = (PN <= 4) ? PN : 6;   // iy tap band (span<=6, proven)
    const int t    = threadIdx.x;
    const int lane = t & 63, col = lane & 15, quad = lane >> 4;
    const int wid  = t >> 6;                  // 0..15
    const int Nt   = wid >> 1, mt = wid & 1;
    const int ty   = Nt >> 1, xh = Nt & 1;
    const int yt   = blockIdx.x & 7, b = blockIdx.x >> 3;
    const int y0   = yt * 4;

    __shared__ half8 Hhi8[816], Hlo8[816];    // 6*34*32 halves = 13056 B each
    __shared__ float cache[IYB][PN][32];      // emb rows, ch-minor
    half_t* Hhi = (half_t*)Hhi8;
    half_t* Hlo = (half_t*)Hlo8;

    const float scale = (float)PN / (float)HH;
    int iy_lo = 0;
    if (PN > 4) {
        int lo = (int)floorf(((float)(y0 - 1) + 0.5f) * scale - 0.5f) - 1;
        lo = lo < 0 ? 0 : lo;
        lo = lo > PN - IYB ? PN - IYB : lo;
        iy_lo = lo;
    }

    // emb gather -> cache (float4 per 4ch; winner idx straight from pk, L2)
    const u64_t* pkb = pk + b * PN * PN;
    for (int i = t; i < IYB * PN * 8; i += 1024) {
        int chg = i & 7, cell = i >> 3;
        int ix = cell % PN, iyb = cell / PN;
        int idx = (int)(unsigned)(pkb[(iy_lo + iyb) * PN + ix] & 0xFFFFFFFFull);
        *(float4*)&cache[iyb][ix][chg * 4] =
            *(const float4*)(emb + (size_t)idx * CH + chg * 4);
    }
    __syncthreads();

    // bicubic staging -> H fp16-split (4 ch per iter; fp32 chain bit-identical
    // to the r3-proven per-element path; windows recomputed per element)
    for (int i = t; i < 1632; i += 1024) {       // 204 cells x 8 ch-groups
        int chg = i & 7, cell = i >> 3;
        int xs = cell % 34, row = cell / 34;
        int gy = y0 - 1 + row, gx = xs - 1;
        float s0 = 0.f, s1 = 0.f, s2 = 0.f, s3 = 0.f;
        if ((unsigned)gy < 32u && (unsigned)gx < 32u) {
            int iy[4], ixv[4]; float wy[4], wxv[4];
            cubic_w(((float)gy + 0.5f) * scale - 0.5f, PN, iy, wy);
            cubic_w(((float)gx + 0.5f) * scale - 0.5f, PN, ixv, wxv);
#pragma unroll
            for (int a = 0; a < 4; a++) {
                const int iyb = iy[a] - iy_lo;
                float r0 = 0.f, r1 = 0.f, r2 = 0.f, r3 = 0.f;
#pragma unroll
                for (int b2 = 0; b2 < 4; b2++) {
                    const float4 tv = *(const float4*)&cache[iyb][ixv[b2]][chg * 4];
                    r0 = fmaf(tv.x, wxv[b2], r0);
                    r1 = fmaf(tv.y, wxv[b2], r1);
                    r2 = fmaf(tv.z, wxv[b2], r2);
                    r3 = fmaf(tv.w, wxv[b2], r3);
                }
                s0 = fmaf(r0, wy[a], s0);
                s1 = fmaf(r1, wy[a], s1);
                s2 = fmaf(r2, wy[a], s2);
                s3 = fmaf(r3, wy[a], s3);
            }
        }
        const int ho = cell * 32 + chg * 4;
        half_t h, l;
        split2(s0, &h, &l); Hhi[ho + 0] = h; Hlo[ho + 0] = l;
        split2(s1, &h, &l); Hhi[ho + 1] = h; Hlo[ho + 1] = l;
        split2(s2, &h, &l); Hhi[ho + 2] = h; Hlo[ho + 2] = l;
        split2(s3, &h, &l); Hhi[ho + 3] = h; Hlo[ho + 3] = l;
    }
    __syncthreads();

    // 9-tap MFMA accumulation; C-init = bias per output row (co)
    const float4 bv = *(const float4*)(bias + mt * 16 + quad * 4);
    floatx4 acc = {bv.x, bv.y, bv.z, bv.w};
#pragma unroll
    for (int tau = 0; tau < 9; tau++) {
        const int dy = tau / 3, dx = tau % 3;
        const int woff = (mt * 9 + tau) * 512 + quad * 128 + col * 8;
        const half8 wh = *(const half8*)(whi + woff);
        const half8 wl = *(const half8*)(wlo + woff);
        const int hoff = ((ty + dy) * 34 + xh * 16 + dx + col) * 32 + quad * 8;
        const half8 hh = *(const half8*)(Hhi + hoff);
        const half8 hl = *(const half8*)(Hlo + hoff);
        acc = __builtin_amdgcn_mfma_f32_16x16x32_f16(wh, hh, acc, 0, 0, 0);
        acc = __builtin_amdgcn_mfma_f32_16x16x32_f16(wh, hl, acc, 0, 0, 0);
        acc = __builtin_amdgcn_mfma_f32_16x16x32_f16(wl, hh, acc, 0, 0, 0);
    }

    // epilogue: residual + store; lane owns pix (y0+ty, xh*16+col), 4 co's
    const int x = xh * 16 + col, y = y0 + ty;
    const int hcell = ((ty + 1) * 34 + (x + 1)) * 32;
    float pv[4];
#pragma unroll
    for (int r = 0; r < 4; r++) {
        const int c = mt * 16 + quad * 4 + r;
        const float hc = (float)Hhi[hcell + c] + (float)Hlo[hcell + c];
        const size_t off = (((size_t)(b * CH + c)) * HH + y) * HH + x;
        const float dv = src[off] - (0.5f * hc + 0.5f * acc[r]);
        dst[off] = dv;
        pv[r] = dv;
    }

    if constexpr (PN_NEXT != 0) {
        constexpr int PSP = 32 / PN_NEXT;        // 16/8/4/2 (<=16: in-wave x)
#pragma unroll
        for (int m = 1; m < PSP; m <<= 1)        // col bits only, stays in quad
#pragma unroll
            for (int r = 0; r < 4; r++) pv[r] += __shfl_xor(pv[r], m, 64);
        if ((col & (PSP - 1)) == 0) {
            const int wx = x / PSP, wy = y / PSP;
#pragma unroll
            for (int r = 0; r < 4; r++) {
                const int c = mt * 16 + quad * 4 + r;
                atomicAdd(zp + ((size_t)((b * PN_NEXT + wy) * PN_NEXT + wx)) * CH + c,
                          pv[r]);
            }
        }
    }
}

// ---------------------------------------------------------------------------
// hits bincount over all scales' packed winners (multi-block, parallel —
// r3 lesson: single-block LDS-hist finalize was a 60us serial tail)
__global__ __launch_bounds__(256) void bincount_kernel(const u64_t* __restrict__ pk,
                                                       float* __restrict__ hits, int n) {
    int i = blockIdx.x * 256 + threadIdx.x;
    if (i < n) {
        int idx = (int)(unsigned)(pk[i] & 0xFFFFFFFFull);
        atomicAdd(&hits[idx], 1.0f);
    }
}

// ---------------------------------------------------------------------------
// perplexity + loss finalize (single block; reads only 4096-entry hist +
// 1024 lacc partials = 20 KB)
__global__ __launch_bounds__(256) void finalize_kernel(const float* __restrict__ hits,
                                                       const float* __restrict__ laccp,
                                                       float* __restrict__ outs) {
    __shared__ float sh[256];
    int t = threadIdx.x;
    // total = NROWS_TOTAL exactly (each row contributes one hit)
    const float tot = (float)NROWS_TOTAL;
    float ent = 0.f;
    for (int v = t; v < VV; v += 256) {
        float p = hits[v] / tot;
        ent += p * logf(p + 1e-10f);
    }
    sh[t] = ent;
    __syncthreads();
    for (int o = 128; o > 0; o >>= 1) {
        if (t < o) sh[t] += sh[t + o];
        __syncthreads();
    }
    float entT = sh[0];            // valid for all after the synced tree
    __syncthreads();
    float ls = 0.f;
    for (int i = t; i < 1024; i += 256) ls += laccp[i];
    sh[t] = ls;
    __syncthreads();
    for (int o = 128; o > 0; o >>= 1) {
        if (t < o) sh[t] += sh[t + o];
        __syncthreads();
    }
    if (t == 0) {
        // loss = SN*(1+BETA)*mean(f^2) = 7.5 * sumsq / 1048576  (f_hat stays 0)
        outs[0] = 7.5f * sh[0] * (1.0f / (float)FELEMS);
        outs[1] = expf(-entT);
    }
}

// ---------------------------------------------------------------------------
extern "C" void kernel_launch(void* const* d_in, const int* in_sizes, int n_in,
                              void* d_out, int out_size, void* d_ws, size_t ws_size,
                              hipStream_t stream) {
    const float* f   = (const float*)d_in[0];   // (32,32,32,32)
    const float* emb = (const float*)d_in[1];   // (4096,32)
    const float* phw = (const float*)d_in[2];   // (4,32,32,3,3)
    const float* phb = (const float*)d_in[3];   // (4,32)
    float* out = (float*)d_out;                 // f_hat (1048576) + loss + perplexity

    float* ws      = (float*)d_ws;
    float* hits    = ws;                              // [0, 4096)
    float* laccp   = ws + 4096;                       // [4096, 5120) partials
    u64_t* pkbase  = (u64_t*)(ws + 8448);             // 43680 u64 -> [8448, 95808)
    float* frest   = ws + 95808;                      // [95808, 1144384)
    half_t* zhi    = (half_t*)(ws + 1144384);         // si=0 z-split (1024 used)
    half_t* zlo    = (half_t*)(ws + 1275456);
    float* nesqh   = ws + 1537600;                    // [1537600, 1541696)
    half_t* ehi    = (half_t*)(ws + 2590272);         // 131072 halves
    half_t* elo    = (half_t*)(ws + 2655808);         // ends 2721344
    float* zp      = ws + 2721344;                    // 348160 f -> ends 3069504
    half_t* whi    = (half_t*)(ws + 3069504);         // 36864 halves
    half_t* wlo    = (half_t*)(ws + 3087936);         // ends 3106368 (12.4 MB)

    // zp slices (zeroed once in prep; each written by exactly one conv)
    float* zp1 = zp;            // PN_NEXT=2:  4096
    float* zp2 = zp + 4096;     // PN_NEXT=4:  16384
    float* zp3 = zp + 20480;    // PN_NEXT=8:  65536
    float* zp4 = zp + 86016;    // PN_NEXT=16: 262144 -> total 348160

    prep_kernel<<<1024, 256, 0, stream>>>(f, emb, phw, whi, wlo, ehi, elo, nesqh,
                                          hits, laccp, zhi, zlo, pkbase, zp, out);

    const int pkoff[6] = {0, 32, 160, 672, 2720, 10912};
    const size_t WFP = 9216;                          // halves per phi frag-pack

    // si=0 (pn=1, sel=0)
    argmin_stage<1, 16><<<dim3(2, 16), 256, 0, stream>>>(zhi, zlo, ehi, elo, nesqh,
                                                         pkbase + pkoff[0]);
    conv_mfma_kernel<1, 2><<<256, 1024, 0, stream>>>(pkbase + pkoff[0], emb,
                                                     whi + 0 * WFP, wlo + 0 * WFP,
                                                     phb + 0 * CH, f, frest, zp1);

    // si=1 (pn=2, sel=0)
    argmin_zp<1, 16, 2><<<dim3(8, 16), 256, 0, stream>>>(zp1, ehi, elo, nesqh,
                                                         pkbase + pkoff[1]);
    conv_mfma_kernel<2, 4><<<256, 1024, 0, stream>>>(pkbase + pkoff[1], emb,
                                                     whi + 0 * WFP, wlo + 0 * WFP,
                                                     phb + 0 * CH, frest, frest, zp2);

    // si=2 (pn=4, sel=1)
    argmin_zp<1, 16, 4><<<dim3(32, 16), 256, 0, stream>>>(zp2, ehi, elo, nesqh,
                                                          pkbase + pkoff[2]);
    conv_mfma_kernel<4, 8><<<256, 1024, 0, stream>>>(pkbase + pkoff[2], emb,
                                                     whi + 1 * WFP, wlo + 1 * WFP,
                                                     phb + 1 * CH, frest, frest, zp3);

    // si=3 (pn=8, sel=2)
    argmin_zp<1, 8, 8><<<dim3(128, 8), 256, 0, stream>>>(zp3, ehi, elo, nesqh,
                                                         pkbase + pkoff[3]);
    conv_mfma_kernel<8, 16><<<256, 1024, 0, stream>>>(pkbase + pkoff[3], emb,
                                                      whi + 2 * WFP, wlo + 2 * WFP,
                                                      phb + 2 * CH, frest, frest, zp4);

    // si=4 (pn=16, sel=3); conv has no pooling (si=5 reads frest directly)
    argmin_zp<2, 4, 16><<<dim3(256, 4), 256, 0, stream>>>(zp4, ehi, elo, nesqh,
                                                          pkbase + pkoff[4]);
    conv_mfma_kernel<16, 0><<<256, 1024, 0, stream>>>(pkbase + pkoff[4], emb,
                                                      whi + 3 * WFP, wlo + 3 * WFP,
                                                      phb + 3 * CH, frest, frest, nullptr);

    // si=5 (pn=32, sel=3): fused identity-pool argmin straight from frest
    argmin5_fused<<<dim3(512, 2), 256, 0, stream>>>(frest, ehi, elo, nesqh,
                                                    pkbase + pkoff[5]);

    bincount_kernel<<<(NROWS_TOTAL + 255) / 256, 256, 0, stream>>>(pkbase, hits, NROWS_TOTAL);
    finalize_kernel<<<1, 256, 0, stream>>>(hits, laccp, out + (out_size - 2));
}